// Round 2
// baseline (4497.036 us; speedup 1.0000x reference)
//
#include <hip/hip_runtime.h>
#include <math.h>

#define B_ 256
#define T_ 128
#define D_ 64
#define H_ 512
#define A_ 128
#define O_ 32

typedef __attribute__((ext_vector_type(8))) short short8;
typedef __attribute__((ext_vector_type(8))) unsigned short ushort8;
typedef __attribute__((ext_vector_type(4))) float floatx4;
typedef __attribute__((ext_vector_type(4))) unsigned int uintx4;
typedef unsigned long long ull;

__device__ __forceinline__ float sp_(float x) {
    return fmaxf(x, 0.f) + log1pf(expf(-fabsf(x)));
}
__device__ __forceinline__ float sigm_(float x) {
    return 1.f / (1.f + expf(-x));
}
__device__ __forceinline__ unsigned short f2bf_(float f) {
    unsigned int u = __float_as_uint(f);
    return (unsigned short)((u + 0x7FFFu + ((u >> 16) & 1u)) >> 16);
}
__device__ __forceinline__ float bf2f_(unsigned short u) {
    return __uint_as_float(((unsigned)u) << 16);
}

// ---- scope-templated raw loads/stores --------------------------------------
// FAST=true  -> sc0 only: L1-bypass, serviced by the XCD-shared L2 (~200 cy).
//               Only taken after the runtime handshake PROVES the 8 blocks of
//               the group can communicate through this exact path (probe +
//               XCC_ID equality + one full bounded trial barrier round), with
//               the verdict AND-reduced over the always-correct sc0 sc1 path.
// FAST=false -> sc0 sc1: MALL-serviced (~900 cy). Always safe (R11 behavior).
template <bool FAST>
__device__ __forceinline__ void ld16x(uintx4& d, const void* p) {
    if constexpr (FAST)
        asm volatile("global_load_dwordx4 %0, %1, off sc0"
                     : "=v"(d) : "v"(p) : "memory");
    else
        asm volatile("global_load_dwordx4 %0, %1, off sc0 sc1"
                     : "=v"(d) : "v"(p) : "memory");
}
template <bool FAST>
__device__ __forceinline__ void ld4x(float& d, const void* p) {
    if constexpr (FAST)
        asm volatile("global_load_dword %0, %1, off sc0"
                     : "=v"(d) : "v"(p) : "memory");
    else
        asm volatile("global_load_dword %0, %1, off sc0 sc1"
                     : "=v"(d) : "v"(p) : "memory");
}
template <bool FAST>
__device__ __forceinline__ unsigned ldu32x(const unsigned* p) {
    unsigned d;
    if constexpr (FAST)
        asm volatile("global_load_dword %0, %1, off sc0\n\t"
                     "s_waitcnt vmcnt(0)"
                     : "=v"(d) : "v"(p) : "memory");
    else
        asm volatile("global_load_dword %0, %1, off sc0 sc1\n\t"
                     "s_waitcnt vmcnt(0)"
                     : "=v"(d) : "v"(p) : "memory");
    return d;
}
template <bool FAST>
__device__ __forceinline__ void stfx(float* p, float v) {
    if constexpr (FAST)
        asm volatile("global_store_dword %0, %1, off sc0"
                     :: "v"(p), "v"(v) : "memory");
    else
        asm volatile("global_store_dword %0, %1, off sc0 sc1"
                     :: "v"(p), "v"(v) : "memory");
}
template <bool FAST>
__device__ __forceinline__ void st64x(ull* p, ull v) {
    if constexpr (FAST)
        asm volatile("global_store_dwordx2 %0, %1, off sc0"
                     :: "v"(p), "v"(v) : "memory");
    else
        asm volatile("global_store_dwordx2 %0, %1, off sc0 sc1"
                     :: "v"(p), "v"(v) : "memory");
}
template <bool FAST>
__device__ __forceinline__ void stu32x(unsigned* p, unsigned v) {
    if constexpr (FAST)
        asm volatile("global_store_dword %0, %1, off sc0"
                     :: "v"(p), "v"(v) : "memory");
    else
        asm volatile("global_store_dword %0, %1, off sc0 sc1"
                     :: "v"(p), "v"(v) : "memory");
}

__device__ __forceinline__ void vmwait4(uintx4& a, uintx4& b, uintx4& c,
                                        uintx4& d) {
    asm volatile("s_waitcnt vmcnt(0)"
                 : "+v"(a), "+v"(b), "+v"(c), "+v"(d)::"memory");
}
__device__ __forceinline__ void vmwait8(uintx4& a, uintx4& b, uintx4& c,
                                        uintx4& d, uintx4& e, uintx4& f,
                                        uintx4& g, uintx4& h) {
    asm volatile("s_waitcnt vmcnt(0)"
                 : "+v"(a), "+v"(b), "+v"(c), "+v"(d), "+v"(e), "+v"(f),
                   "+v"(g), "+v"(h)::"memory");
}
__device__ __forceinline__ void vmwait16f(float& a0, float& a1, float& a2,
                                          float& a3, float& a4, float& a5,
                                          float& a6, float& a7, float& b0,
                                          float& b1, float& b2, float& b3,
                                          float& b4, float& b5, float& b6,
                                          float& b7) {
    asm volatile("s_waitcnt vmcnt(0)"
                 : "+v"(a0), "+v"(a1), "+v"(a2), "+v"(a3), "+v"(a4), "+v"(a5),
                   "+v"(a6), "+v"(a7), "+v"(b0), "+v"(b1), "+v"(b2), "+v"(b3),
                   "+v"(b4), "+v"(b5), "+v"(b6), "+v"(b7)::"memory");
}
__device__ __forceinline__ floatx4 u2f_(uintx4 u) {
    union { uintx4 u; floatx4 f; } c;
    c.u = u;
    return c.f;
}

// ---------------- init: hpack = 0, flags = 0 --------------------------------
__global__ void init_kernel(unsigned short* __restrict__ hpack,
                            unsigned* __restrict__ bar) {
    int i = blockIdx.x * 256 + threadIdx.x;
    if (i < B_ * H_) hpack[i] = 0;
    if (i < 8192) bar[i] = 0u;
}

// -------- pack all weights into MFMA B-frag bf16 order ----------------------
__global__ void pack_w_kernel(const float* __restrict__ W_gd,
                              const float* __restrict__ W_tau,
                              const float* __restrict__ Wk,
                              const float* __restrict__ Wv,
                              unsigned short* __restrict__ Wpack) {
    int gid = blockIdx.x * 256 + threadIdx.x;
    if (gid >= 1114112) return;
    int j = gid & 7;
    int l = (gid >> 3) & 63;
    int kpart = (l >> 4) * 8 + j;
    int npart = l & 15;
    float v;
    if (gid < 786432) {
        int f = gid >> 9;
        int s = f % 3;
        int rem = f / 3;
        int kb = rem & 15, ct = rem >> 4;
        int k = kb * 32 + kpart;
        int c = ct * 16 + npart;
        if (s == 0)      v = W_gd[(size_t)(D_ + k) * 1024 + c];
        else if (s == 1) v = W_gd[(size_t)(D_ + k) * 1024 + 512 + c];
        else             v = W_tau[(size_t)k * 512 + c];
    } else if (gid < 851968) {
        int r = gid - 786432;
        int f = r >> 9;
        int s = f & 1, kb = (f >> 1) & 1, ct = f >> 2;
        int k = kb * 32 + kpart;
        int c = ct * 16 + npart;
        v = W_gd[(size_t)k * 1024 + s * 512 + c];
    } else if (gid < 983040) {
        int r = gid - 851968;
        int f = r >> 9;
        int s = f & 1, kb = (f >> 1) & 3, ct = f >> 3;
        int k = kb * 32 + kpart;
        int c = ct * 16 + npart;
        v = W_gd[(size_t)(D_ + H_ + k) * 1024 + s * 512 + c];
    } else {
        int r = gid - 983040;
        int f = r >> 9;
        int kb = f & 15, c4 = f >> 4;
        int k = kb * 32 + kpart;
        int n = (c4 & 7) * 16 + npart;
        v = (c4 < 8) ? Wk[(size_t)k * A_ + n] : Wv[(size_t)k * A_ + n];
    }
    Wpack[gid] = f2bf_(v);
}

// ---- group barrier: 8 blocks, per-block flag slots (scope-templated) -------
template <bool FAST>
__device__ __forceinline__ void gsyncT(unsigned* flags, int j, unsigned cnt) {
    asm volatile("s_waitcnt vmcnt(0)" ::: "memory");  // drain data stores
    __syncthreads();
    if (threadIdx.x == 0) stu32x<FAST>(flags + j * 64, cnt);
    if (threadIdx.x < 8) {
        while (ldu32x<FAST>(flags + (int)threadIdx.x * 64) < cnt) {
            __builtin_amdgcn_s_sleep(1);
        }
    }
    __syncthreads();
}

struct P {
    const float *x, *dts, *Wq, *bq, *bk, *bv, *b_gd, *b_tau, *gleak, *cm,
        *W_fc, *b_fc;
    float *h, *ctx, *out, *Kpart, *Vpart;
    unsigned short* Kh;  // K: [B][T][A] bf16 (block-private rows, plain ld/st)
    const unsigned short *Wy, *Wx, *Wc, *Wkv;
    unsigned short *hpack, *yapack, *ybpack;  // layout [m_tile][strip][row][col]
    unsigned* bar;
};

struct Shm {
    float WqL[D_ * 129];
    float xs4[2][D_];
    float q4[2][A_];
    float sc4[2][T_];
    float red[2][2];
    alignas(16) unsigned short AsL[32 * 256];  // 16 KB staged A
    alignas(16) unsigned short ypbuf[4 * 256]; // 2 KB transpose
    alignas(16) unsigned short As2[2 * 512];   // kv h A-frags
    unsigned short VhL[2][A_][136];            // ~70 KB V history
    unsigned xcs[8];                           // handshake scratch
};

template <bool FAST>
__device__ __forceinline__ void run_body(const P& p, Shm& sh) {
    const int tid = threadIdx.x;
    const int bid = blockIdx.x;
    const int lane = tid & 63;
    const int wave = tid >> 6;            // 0..3
    const int g = bid & 15;               // group of 8 blocks (bid%8 -> XCD)
    const int j = bid >> 4;               // block within group 0..7
    const int ct = j * 4 + wave;          // channel strip 0..31
    unsigned* flags = p.bar + g * 512;
    unsigned cnt = 0;

    const int quad = lane >> 4;
    const int c = ct * 16 + (lane & 15);
    const float btau = p.b_tau[c];
    const float lk = sp_(p.cm[c]) + sp_(p.gleak[c]) + 1e-6f;
    const float bgd_g = p.b_gd[c];
    const float bgd_d = p.b_gd[512 + c];
    const int aoff = (quad >> 1) * 256 + (lane & 15) * 16 + (quad & 1) * 8;
    const int ypw = wave * 256 + (lane & 15);

    const int sub = tid >> 7;             // 0..1
    const int tl = tid & 127;
    const int r = g * 16 + j * 2 + sub;   // this block's 2 attention rows
    const int rrow = r & 15;

    // ---- persistent register weights: 60 frags (240 VGPRs) ----
    short8 wg[16], wd[16], wt[16];
    short8 wxg[2], wxd[2], wcg[4], wcd[4];
    {
        const short8* Wy8 = (const short8*)p.Wy;
        #pragma unroll
        for (int kb = 0; kb < 16; ++kb) {
            wg[kb] = Wy8[((ct * 16 + kb) * 3 + 0) * 64 + lane];
            wd[kb] = Wy8[((ct * 16 + kb) * 3 + 1) * 64 + lane];
            wt[kb] = Wy8[((ct * 16 + kb) * 3 + 2) * 64 + lane];
        }
        const short8* Wx8 = (const short8*)p.Wx;
        const short8* Wc8 = (const short8*)p.Wc;
        #pragma unroll
        for (int kb = 0; kb < 2; ++kb) {
            wxg[kb] = Wx8[((ct * 2 + kb) * 2 + 0) * 64 + lane];
            wxd[kb] = Wx8[((ct * 2 + kb) * 2 + 1) * 64 + lane];
        }
        #pragma unroll
        for (int kb = 0; kb < 4; ++kb) {
            wcg[kb] = Wc8[((ct * 4 + kb) * 2 + 0) * 64 + lane];
            wcd[kb] = Wc8[((ct * 4 + kb) * 2 + 1) * 64 + lane];
        }
    }

    for (int i = tid; i < D_ * A_; i += 256) {
        int d = i >> 7, a = i & 127;
        sh.WqL[d * 129 + a] = p.Wq[i];
    }

    floatx4 hreg = {0.f, 0.f, 0.f, 0.f};
    floatx4 rk1, rk2, rk3, baseg, based, ycur, dt4;

    const short8* Wkv8 = (const short8*)p.Wkv;

    __syncthreads();  // WqL ready

    for (int t = 0; t < T_; ++t) {
        // ---------- phase A: K/V merge of t-1 + attention (2 rows) ----------
        {
            if (t > 0) {
                // batched: issue all 16 loads, one waitcnt, then sum
                float kk[8], vv[8];
                #pragma unroll
                for (int jj = 0; jj < 8; ++jj) {
                    ld4x<FAST>(kk[jj],
                               p.Kpart + ((g * 8 + jj) * 16 + rrow) * 128 + tl);
                    ld4x<FAST>(vv[jj],
                               p.Vpart + ((g * 8 + jj) * 16 + rrow) * 128 + tl);
                }
                vmwait16f(kk[0], kk[1], kk[2], kk[3], kk[4], kk[5], kk[6],
                          kk[7], vv[0], vv[1], vv[2], vv[3], vv[4], vv[5],
                          vv[6], vv[7]);
                float ks = p.bk[tl], vs = p.bv[tl];
                #pragma unroll
                for (int jj = 0; jj < 8; ++jj) {
                    ks += kk[jj];
                    vs += vv[jj];
                }
                p.Kh[(size_t)(r * T_ + (t - 1)) * A_ + tl] = f2bf_(ks);
                sh.VhL[sub][tl][t - 1] = f2bf_(vs);
            }
            if (tl < 16)
                ((float4*)sh.xs4[sub])[tl] =
                    ((const float4*)&p.x[(r * T_ + t) * D_])[tl];
            __syncthreads();
            float qa = p.bq[tl];
            #pragma unroll 8
            for (int d = 0; d < D_; ++d)
                qa += sh.xs4[sub][d] * sh.WqL[d * 129 + tl];
            sh.q4[sub][tl] = qa;
            __syncthreads();
            if (t == 0) {
                stfx<FAST>(p.ctx + r * A_ + tl, 0.f);
            } else {
                const float rscale = 0.08838834764831845f;  // 1/sqrt(128)
                const int grp = tl >> 4, ln = tl & 15;
                float qv[8];
                #pragma unroll
                for (int i = 0; i < 8; ++i) qv[i] = sh.q4[sub][ln * 8 + i];
                for (int s = grp; s < t; s += 8) {
                    ushort8 k8 = *((const ushort8*)(p.Kh +
                                     (size_t)(r * T_ + s) * A_) + ln);
                    float a2 = 0.f;
                    #pragma unroll
                    for (int i = 0; i < 8; ++i) a2 += bf2f_(k8[i]) * qv[i];
                    #pragma unroll
                    for (int off = 8; off > 0; off >>= 1)
                        a2 += __shfl_xor(a2, off, 16);
                    if (ln == 0) sh.sc4[sub][s] = a2 * rscale;
                }
                __syncthreads();
                float mloc = -1e30f;
                for (int s = tl; s < t; s += 128)
                    mloc = fmaxf(mloc, sh.sc4[sub][s]);
                #pragma unroll
                for (int off = 32; off > 0; off >>= 1)
                    mloc = fmaxf(mloc, __shfl_xor(mloc, off, 64));
                if (lane == 0) sh.red[sub][wave & 1] = mloc;
                __syncthreads();
                float m = fmaxf(sh.red[sub][0], sh.red[sub][1]);
                float ssum = 0.f;
                for (int s = tl; s < t; s += 128) {
                    float e = expf(sh.sc4[sub][s] - m);
                    sh.sc4[sub][s] = e;
                    ssum += e;
                }
                #pragma unroll
                for (int off = 32; off > 0; off >>= 1)
                    ssum += __shfl_xor(ssum, off, 64);
                __syncthreads();
                if (lane == 0) sh.red[sub][wave & 1] = ssum;
                __syncthreads();
                float rs = 1.f / (sh.red[sub][0] + sh.red[sub][1]);
                const unsigned short* Vrow = &sh.VhL[sub][tl][0];
                float ca0 = 0.f, ca1 = 0.f;
                int s0 = 0;
                for (; s0 + 16 <= t; s0 += 16) {
                    ushort8 v0 = *(const ushort8*)(Vrow + s0);
                    ushort8 v1 = *(const ushort8*)(Vrow + s0 + 8);
                    #pragma unroll
                    for (int i = 0; i < 8; ++i) {
                        ca0 += sh.sc4[sub][s0 + i] * bf2f_(v0[i]);
                        ca1 += sh.sc4[sub][s0 + 8 + i] * bf2f_(v1[i]);
                    }
                }
                if (s0 + 8 <= t) {
                    ushort8 v0 = *(const ushort8*)(Vrow + s0);
                    #pragma unroll
                    for (int i = 0; i < 8; ++i)
                        ca0 += sh.sc4[sub][s0 + i] * bf2f_(v0[i]);
                    s0 += 8;
                }
                for (; s0 < t; ++s0) ca0 += sh.sc4[sub][s0] * bf2f_(Vrow[s0]);
                stfx<FAST>(p.ctx + r * A_ + tl, (ca0 + ca1) * rs);
            }
        }
        gsyncT<FAST>(flags, j, ++cnt);

        // ---------- phase B: stage1 + base fold (register weights) ----------
        {
            // stage m_tile's hpack (16 KB) -> LDS: 4 batched 16B loads
            {
                const unsigned short* src = p.hpack + g * 8192;
                uintx4 av[4];
                #pragma unroll
                for (int i = 0; i < 4; ++i)
                    ld16x<FAST>(av[i], src + (size_t)tid * 8 + i * 2048);
                vmwait4(av[0], av[1], av[2], av[3]);
                #pragma unroll
                for (int i = 0; i < 4; ++i)
                    ((uintx4*)sh.AsL)[tid + i * 256] = av[i];
            }
            // ctx row: 8 batched 16B loads
            const int mrow = lane & 15;
            const int kq = lane >> 4;
            const float* crow = &p.ctx[(g * 16 + mrow) * A_];
            uintx4 cc[8];
            #pragma unroll
            for (int kb = 0; kb < 4; ++kb) {
                ld16x<FAST>(cc[2 * kb], crow + kb * 32 + kq * 8);
                ld16x<FAST>(cc[2 * kb + 1], crow + kb * 32 + kq * 8 + 4);
            }
            vmwait8(cc[0], cc[1], cc[2], cc[3], cc[4], cc[5], cc[6], cc[7]);
            __syncthreads();  // AsL ready

            #pragma unroll
            for (int i = 0; i < 4; ++i)
                dt4[i] = p.dts[(g * 16 + quad * 4 + i) * T_ + t];

            floatx4 bg = {0.f, 0.f, 0.f, 0.f};
            floatx4 bd = {0.f, 0.f, 0.f, 0.f};
            const float4* xrow =
                (const float4*)&p.x[((g * 16 + mrow) * T_ + t) * D_];
            #pragma unroll
            for (int kb = 0; kb < 2; ++kb) {
                float4 u = xrow[kb * 8 + kq * 2], v = xrow[kb * 8 + kq * 2 + 1];
                short8 ax;
                ax[0] = (short)f2bf_(u.x); ax[1] = (short)f2bf_(u.y);
                ax[2] = (short)f2bf_(u.z); ax[3] = (short)f2bf_(u.w);
                ax[4] = (short)f2bf_(v.x); ax[5] = (short)f2bf_(v.y);
                ax[6] = (short)f2bf_(v.z); ax[7] = (short)f2bf_(v.w);
                bg = __builtin_amdgcn_mfma_f32_16x16x32_bf16(ax, wxg[kb], bg, 0, 0, 0);
                bd = __builtin_amdgcn_mfma_f32_16x16x32_bf16(ax, wxd[kb], bd, 0, 0, 0);
            }
            #pragma unroll
            for (int kb = 0; kb < 4; ++kb) {
                floatx4 f0 = u2f_(cc[2 * kb]), f1 = u2f_(cc[2 * kb + 1]);
                short8 ac;
                ac[0] = (short)f2bf_(f0[0]); ac[1] = (short)f2bf_(f0[1]);
                ac[2] = (short)f2bf_(f0[2]); ac[3] = (short)f2bf_(f0[3]);
                ac[4] = (short)f2bf_(f1[0]); ac[5] = (short)f2bf_(f1[1]);
                ac[6] = (short)f2bf_(f1[2]); ac[7] = (short)f2bf_(f1[3]);
                bg = __builtin_amdgcn_mfma_f32_16x16x32_bf16(ac, wcg[kb], bg, 0, 0, 0);
                bd = __builtin_amdgcn_mfma_f32_16x16x32_bf16(ac, wcd[kb], bd, 0, 0, 0);
            }
            floatx4 ag = {0.f, 0.f, 0.f, 0.f};
            floatx4 ad = {0.f, 0.f, 0.f, 0.f};
            floatx4 at = {0.f, 0.f, 0.f, 0.f};
            #pragma unroll
            for (int kb = 0; kb < 16; ++kb) {
                short8 a = *(const short8*)(sh.AsL + kb * 512 + aoff);
                ag = __builtin_amdgcn_mfma_f32_16x16x32_bf16(a, wg[kb], ag, 0, 0, 0);
                ad = __builtin_amdgcn_mfma_f32_16x16x32_bf16(a, wd[kb], ad, 0, 0, 0);
                at = __builtin_amdgcn_mfma_f32_16x16x32_bf16(a, wt[kb], at, 0, 0, 0);
            }
            #pragma unroll
            for (int i = 0; i < 4; ++i) {
                baseg[i] = bg[i] + bgd_g;
                based[i] = bd[i] + bgd_d;
                float gate = ag[i] + baseg[i];
                float dyn = ad[i] + based[i];
                float tau = sp_(at[i] + btau);
                float ki = (sigm_(gate) * tanhf(dyn) - hreg[i]) / (tau + lk);
                rk1[i] = ki;
                float yn = hreg[i] + dt4[i] * ki * (1.f / 3.f);
                ycur[i] = yn;
                sh.ypbuf[ypw + (quad * 4 + i) * 16] = f2bf_(yn);
            }
            __syncthreads();
            st64x<FAST>((ull*)p.yapack + g * 2048 + j * 256 + tid,
                        ((const ull*)sh.ypbuf)[tid]);
        }
        gsyncT<FAST>(flags, j, ++cnt);

        // ---------- stages 2..4 ----------
        #pragma unroll 1
        for (int stage = 2; stage <= 4; ++stage) {
            const unsigned short* ysrc =
                (stage == 2) ? p.yapack : (stage == 3) ? p.ybpack : p.yapack;
            unsigned short* ydst =
                (stage == 2) ? p.ybpack : (stage == 3) ? p.yapack : p.hpack;
            {
                const unsigned short* src = ysrc + g * 8192;
                uintx4 av[4];
                #pragma unroll
                for (int i = 0; i < 4; ++i)
                    ld16x<FAST>(av[i], src + (size_t)tid * 8 + i * 2048);
                vmwait4(av[0], av[1], av[2], av[3]);
                #pragma unroll
                for (int i = 0; i < 4; ++i)
                    ((uintx4*)sh.AsL)[tid + i * 256] = av[i];
            }
            __syncthreads();
            floatx4 ag = {0.f, 0.f, 0.f, 0.f};
            floatx4 ad = {0.f, 0.f, 0.f, 0.f};
            floatx4 at = {0.f, 0.f, 0.f, 0.f};
            #pragma unroll
            for (int kb = 0; kb < 16; ++kb) {
                short8 a = *(const short8*)(sh.AsL + kb * 512 + aoff);
                ag = __builtin_amdgcn_mfma_f32_16x16x32_bf16(a, wg[kb], ag, 0, 0, 0);
                ad = __builtin_amdgcn_mfma_f32_16x16x32_bf16(a, wd[kb], ad, 0, 0, 0);
                at = __builtin_amdgcn_mfma_f32_16x16x32_bf16(a, wt[kb], at, 0, 0, 0);
            }
            const int lane_p = ((c >> 3) & 3) * 16;
            #pragma unroll
            for (int i = 0; i < 4; ++i) {
                float gate = ag[i] + baseg[i];
                float dyn = ad[i] + based[i];
                float tau = sp_(at[i] + btau);
                float ki = (sigm_(gate) * tanhf(dyn) - ycur[i]) / (tau + lk);
                float yn;
                if (stage == 2) {
                    rk2[i] = ki;
                    yn = hreg[i] + dt4[i] * (ki - rk1[i] * (1.f / 3.f));
                } else if (stage == 3) {
                    rk3[i] = ki;
                    yn = hreg[i] + dt4[i] * (rk1[i] - rk2[i] + ki);
                } else {
                    yn = hreg[i] +
                         dt4[i] * (rk1[i] + 3.f * rk2[i] + 3.f * rk3[i] + ki) * 0.125f;
                    hreg[i] = yn;
                }
                ycur[i] = yn;
                sh.ypbuf[ypw + (quad * 4 + i) * 16] = f2bf_(yn);
                if (stage == 4)
                    sh.As2[(wave >> 1) * 512 + (c & 7) +
                           (lane_p + quad * 4 + i) * 8] = f2bf_(yn);
            }
            __syncthreads();
            st64x<FAST>((ull*)ydst + g * 2048 + j * 256 + tid,
                        ((const ull*)sh.ypbuf)[tid]);
            if (stage == 4) {
                #pragma unroll
                for (int h4 = 0; h4 < 4; ++h4) {
                    const int c4 = wave + h4 * 4;  // 0..15 (0..7=K, 8..15=V)
                    floatx4 acc = {0.f, 0.f, 0.f, 0.f};
                    #pragma unroll
                    for (int kk2 = 0; kk2 < 2; ++kk2) {
                        short8 a = *(const short8*)(sh.As2 + (kk2 * 64 + lane) * 8);
                        acc = __builtin_amdgcn_mfma_f32_16x16x32_bf16(
                            a, Wkv8[(c4 * 16 + (j * 2 + kk2)) * 64 + lane], acc,
                            0, 0, 0);
                    }
                    const int ac = (c4 & 7) * 16 + (lane & 15);
                    float* part = (c4 < 8) ? p.Kpart : p.Vpart;
                    #pragma unroll
                    for (int i = 0; i < 4; ++i)
                        stfx<FAST>(part +
                                       ((g * 8 + j) * 16 + quad * 4 + i) * 128 +
                                       ac,
                                   acc[i]);
                }
            }
            gsyncT<FAST>(flags, j, ++cnt);
        }
    }

    // ---------- write final h, then fc ----------
    #pragma unroll
    for (int i = 0; i < 4; ++i)
        stfx<FAST>(p.h + (g * 16 + quad * 4 + i) * H_ + c, hreg[i]);
    gsyncT<FAST>(flags, j, ++cnt);
    {
        const int o = tl & 31, ks = tl >> 5;  // ks 0..3
        float acc = 0.f;
        const float* hrow = p.h + r * H_ + ks * 128;
        const float* wcol = p.W_fc + ks * 128 * O_ + o;
        #pragma unroll 1
        for (int rd = 0; rd < 4; ++rd) {
            uintx4 hh[8];
            #pragma unroll
            for (int i = 0; i < 8; ++i)
                ld16x<FAST>(hh[i], hrow + rd * 32 + i * 4);
            vmwait8(hh[0], hh[1], hh[2], hh[3], hh[4], hh[5], hh[6], hh[7]);
            #pragma unroll
            for (int i = 0; i < 8; ++i) {
                floatx4 f = u2f_(hh[i]);
                #pragma unroll
                for (int e = 0; e < 4; ++e)
                    acc += f[e] * wcol[(rd * 32 + i * 4 + e) * O_];
            }
        }
        sh.sc4[sub][tl] = acc;
        __syncthreads();
        if (ks == 0)
            p.out[r * O_ + o] = acc + sh.sc4[sub][o + 32] + sh.sc4[sub][o + 64] +
                                sh.sc4[sub][o + 96] + p.b_fc[o];
    }
}

__global__ __launch_bounds__(256, 1) void fused_kernel(P p) {
    __shared__ Shm sh;
    const int tid = threadIdx.x;
    const int bid = blockIdx.x;
    const int g = bid & 15;
    const int j = bid >> 4;
    unsigned* flags = p.bar + g * 512;

    // ---- R13 handshake (all spins bounded except the final verdict, which
    // every block is guaranteed to store). Line discipline: probe/trial slots
    // (+32, +33) live on the 2nd 128B line of the block's 256B flag slot and
    // are ONLY ever touched sc0-only. Verdict (+1) and sync flag (+0) live on
    // the 1st line, never sc0-dirtied before the verdict completes.
    //
    // Phase 1 (probe, bounded): store XCC_ID+1 via sc0-only; see all 8 AND
    //   all ids equal -> ok.
    // Phase 2 (trial, bounded): one full barrier round through the exact
    //   sc0-only mechanism used by the main loop. Catches any visibility
    //   failure at bounded cost instead of hanging the main loop.
    // Phase 3 (verdict, unanimous): AND-reduce over the always-correct
    //   sc0 sc1 path. Mixed fast/slow within a group is impossible.
    unsigned myxcc;
    asm volatile("s_getreg_b32 %0, hwreg(HW_REG_XCC_ID)" : "=s"(myxcc));
    myxcc = (myxcc & 15u) + 1u;
    if (tid == 0) stu32x<true>(flags + j * 64 + 32, myxcc);
    if (tid < 8) {
        unsigned v = 0;
        for (int it = 0; it < 8192; ++it) {
            v = ldu32x<true>(flags + tid * 64 + 32);
            if (v) break;
            __builtin_amdgcn_s_sleep(2);
        }
        sh.xcs[tid] = (v == myxcc) ? 1u : 0u;  // saw probe AND same XCC id
    }
    __syncthreads();
    bool ok8 = true;
    #pragma unroll
    for (int i = 0; i < 8; ++i) ok8 = ok8 && (sh.xcs[i] != 0u);
    __syncthreads();  // everyone done reading xcs before reuse

    // Phase 2: bounded trial round (block-uniform branch; skipping blocks
    // simply never store their trial flag, so participants time out -> fail).
    bool trial_ok = false;
    if (ok8) {
        if (tid == 0) stu32x<true>(flags + j * 64 + 33, 1u);
        if (tid < 8) {
            unsigned v = 0;
            for (int it = 0; it < 8192; ++it) {
                v = ldu32x<true>(flags + tid * 64 + 33);
                if (v) break;
                __builtin_amdgcn_s_sleep(2);
            }
            sh.xcs[tid] = v ? 1u : 0u;
        }
        __syncthreads();
        trial_ok = true;
        #pragma unroll
        for (int i = 0; i < 8; ++i) trial_ok = trial_ok && (sh.xcs[i] != 0u);
        __syncthreads();
    }

    // Phase 3: unanimous verdict via system scope (every block stores -> no
    // deadlock; poll is the only unbounded wait and is guaranteed to finish).
    if (tid == 0) stu32x<false>(flags + j * 64 + 1, trial_ok ? 2u : 1u);
    if (tid < 8) {
        unsigned v;
        while ((v = ldu32x<false>(flags + tid * 64 + 1)) == 0u)
            __builtin_amdgcn_s_sleep(1);
        sh.xcs[tid] = (v == 2u) ? 1u : 0u;
    }
    __syncthreads();
    bool same8 = true;
    #pragma unroll
    for (int i = 0; i < 8; ++i) same8 = same8 && (sh.xcs[i] != 0u);

    if (same8)
        run_body<true>(p, sh);   // XCD-L2 exchange (~200 cy round trips)
    else
        run_body<false>(p, sh);  // MALL exchange (R11 behavior)
}

extern "C" void kernel_launch(void* const* d_in, const int* in_sizes, int n_in,
                              void* d_out, int out_size, void* d_ws,
                              size_t ws_size, hipStream_t stream) {
    (void)in_sizes; (void)n_in; (void)out_size; (void)ws_size;
    P p;
    p.x = (const float*)d_in[0];
    p.dts = (const float*)d_in[1];
    p.Wq = (const float*)d_in[2];
    p.bq = (const float*)d_in[3];
    const float* Wk = (const float*)d_in[4];
    p.bk = (const float*)d_in[5];
    const float* Wv = (const float*)d_in[6];
    p.bv = (const float*)d_in[7];
    const float* W_gd = (const float*)d_in[8];
    p.b_gd = (const float*)d_in[9];
    const float* W_tau = (const float*)d_in[10];
    p.b_tau = (const float*)d_in[11];
    p.gleak = (const float*)d_in[12];
    p.cm = (const float*)d_in[13];
    p.W_fc = (const float*)d_in[14];
    p.b_fc = (const float*)d_in[15];
    p.out = (float*)d_out;

    float* ws = (float*)d_ws;
    p.h = ws;                            // B*H fp32
    p.ctx = p.h + B_ * H_;               // B*A fp32
    p.Kpart = p.ctx + B_ * A_;           // 128*16*128 fp32
    p.Vpart = p.Kpart + 262144;
    unsigned short* Wpack = (unsigned short*)(p.Vpart + 262144);
    p.Wy = Wpack;                        // 786432 ushorts
    p.Wx = Wpack + 786432;               // 65536
    p.Wc = Wpack + 851968;               // 131072
    p.Wkv = Wpack + 983040;              // 131072
    p.hpack = Wpack + 1114112;           // B*H ushorts, strip-tile layout
    p.yapack = p.hpack + B_ * H_;
    p.ybpack = p.yapack + B_ * H_;
    p.Kh = p.ybpack + B_ * H_;           // B*T*A bf16 (block-private rows)
    p.bar = (unsigned*)(p.Kh + (size_t)B_ * T_ * A_);  // 8192 uints (flags)

    init_kernel<<<512, 256, 0, stream>>>(p.hpack, p.bar);
    pack_w_kernel<<<4352, 256, 0, stream>>>(W_gd, W_tau, Wk, Wv, Wpack);

    // 128 blocks x 256 threads, launch_bounds(256,1). R11: batched raw
    // `global_load sc0 sc1` + single operand-tied waitcnt removed per-load
    // serial MALL round trips. R12/R13: all 8 blocks of a group share bid%8
    // => same XCD under round-robin dispatch; a runtime handshake (probe +
    // XCC_ID equality + bounded trial barrier round through the sc0-only
    // path itself, verdict via system scope) switches ALL intra-group
    // exchange to sc0-only, keeping it resident in the XCD-shared L2
    // (~200 cy instead of ~900 cy MALL). Placement/mechanism failure is
    // detected at bounded cost and falls back to the R11 system-scope path.
    fused_kernel<<<dim3(128), dim3(256), 0, stream>>>(p);
}

// Round 4
// 3759.009 us; speedup vs baseline: 1.1963x; 1.1963x over previous
//
#include <hip/hip_runtime.h>
#include <math.h>

#define B_ 256
#define T_ 128
#define D_ 64
#define H_ 512
#define A_ 128
#define O_ 32

typedef __attribute__((ext_vector_type(8))) short short8;
typedef __attribute__((ext_vector_type(8))) unsigned short ushort8;
typedef __attribute__((ext_vector_type(4))) float floatx4;
typedef __attribute__((ext_vector_type(4))) unsigned int uintx4;
typedef unsigned long long ull;

__device__ __forceinline__ float sp_(float x) {
    return fmaxf(x, 0.f) + log1pf(expf(-fabsf(x)));
}
__device__ __forceinline__ float sigm_(float x) {
    return 1.f / (1.f + expf(-x));
}
__device__ __forceinline__ unsigned short f2bf_(float f) {
    unsigned int u = __float_as_uint(f);
    return (unsigned short)((u + 0x7FFFu + ((u >> 16) & 1u)) >> 16);
}
__device__ __forceinline__ float bf2f_(unsigned short u) {
    return __uint_as_float(((unsigned)u) << 16);
}

// ---- scope-templated raw loads/stores --------------------------------------
// FAST=true  -> sc0 only: L1-bypass, serviced by the XCD-shared L2 (~200 cy).
//               Only taken when the group's 8 blocks are PROVEN same-XCD
//               (runtime roster built from HW_REG_XCC_ID) AND a bounded trial
//               through this exact path succeeded, with the verdict
//               AND-reduced over the always-correct sc0 sc1 path.
// FAST=false -> sc0 sc1: MALL-serviced (~900 cy). Always safe (R11 behavior).
template <bool FAST>
__device__ __forceinline__ void ld16x(uintx4& d, const void* p) {
    if constexpr (FAST)
        asm volatile("global_load_dwordx4 %0, %1, off sc0"
                     : "=v"(d) : "v"(p) : "memory");
    else
        asm volatile("global_load_dwordx4 %0, %1, off sc0 sc1"
                     : "=v"(d) : "v"(p) : "memory");
}
template <bool FAST>
__device__ __forceinline__ void ld4x(float& d, const void* p) {
    if constexpr (FAST)
        asm volatile("global_load_dword %0, %1, off sc0"
                     : "=v"(d) : "v"(p) : "memory");
    else
        asm volatile("global_load_dword %0, %1, off sc0 sc1"
                     : "=v"(d) : "v"(p) : "memory");
}
template <bool FAST>
__device__ __forceinline__ unsigned ldu32x(const unsigned* p) {
    unsigned d;
    if constexpr (FAST)
        asm volatile("global_load_dword %0, %1, off sc0\n\t"
                     "s_waitcnt vmcnt(0)"
                     : "=v"(d) : "v"(p) : "memory");
    else
        asm volatile("global_load_dword %0, %1, off sc0 sc1\n\t"
                     "s_waitcnt vmcnt(0)"
                     : "=v"(d) : "v"(p) : "memory");
    return d;
}
template <bool FAST>
__device__ __forceinline__ void stfx(float* p, float v) {
    if constexpr (FAST)
        asm volatile("global_store_dword %0, %1, off sc0"
                     :: "v"(p), "v"(v) : "memory");
    else
        asm volatile("global_store_dword %0, %1, off sc0 sc1"
                     :: "v"(p), "v"(v) : "memory");
}
template <bool FAST>
__device__ __forceinline__ void st64x(ull* p, ull v) {
    if constexpr (FAST)
        asm volatile("global_store_dwordx2 %0, %1, off sc0"
                     :: "v"(p), "v"(v) : "memory");
    else
        asm volatile("global_store_dwordx2 %0, %1, off sc0 sc1"
                     :: "v"(p), "v"(v) : "memory");
}
template <bool FAST>
__device__ __forceinline__ void stu32x(unsigned* p, unsigned v) {
    if constexpr (FAST)
        asm volatile("global_store_dword %0, %1, off sc0"
                     :: "v"(p), "v"(v) : "memory");
    else
        asm volatile("global_store_dword %0, %1, off sc0 sc1"
                     :: "v"(p), "v"(v) : "memory");
}

__device__ __forceinline__ void vmwait4(uintx4& a, uintx4& b, uintx4& c,
                                        uintx4& d) {
    asm volatile("s_waitcnt vmcnt(0)"
                 : "+v"(a), "+v"(b), "+v"(c), "+v"(d)::"memory");
}
__device__ __forceinline__ void vmwait8(uintx4& a, uintx4& b, uintx4& c,
                                        uintx4& d, uintx4& e, uintx4& f,
                                        uintx4& g, uintx4& h) {
    asm volatile("s_waitcnt vmcnt(0)"
                 : "+v"(a), "+v"(b), "+v"(c), "+v"(d), "+v"(e), "+v"(f),
                   "+v"(g), "+v"(h)::"memory");
}
__device__ __forceinline__ void vmwait16f(float& a0, float& a1, float& a2,
                                          float& a3, float& a4, float& a5,
                                          float& a6, float& a7, float& b0,
                                          float& b1, float& b2, float& b3,
                                          float& b4, float& b5, float& b6,
                                          float& b7) {
    asm volatile("s_waitcnt vmcnt(0)"
                 : "+v"(a0), "+v"(a1), "+v"(a2), "+v"(a3), "+v"(a4), "+v"(a5),
                   "+v"(a6), "+v"(a7), "+v"(b0), "+v"(b1), "+v"(b2), "+v"(b3),
                   "+v"(b4), "+v"(b5), "+v"(b6), "+v"(b7)::"memory");
}
__device__ __forceinline__ floatx4 u2f_(uintx4 u) {
    union { uintx4 u; floatx4 f; } c;
    c.u = u;
    return c.f;
}

// ---------------- init: hpack = 0, flags+roster = 0 --------------------------
__global__ void init_kernel(unsigned short* __restrict__ hpack,
                            unsigned* __restrict__ bar) {
    int i = blockIdx.x * 256 + threadIdx.x;
    if (i < B_ * H_) hpack[i] = 0;
    if (i < 8192 + 64) bar[i] = 0u;   // flags + roster/vote scratch
}

// -------- pack all weights into MFMA B-frag bf16 order ----------------------
__global__ void pack_w_kernel(const float* __restrict__ W_gd,
                              const float* __restrict__ W_tau,
                              const float* __restrict__ Wk,
                              const float* __restrict__ Wv,
                              unsigned short* __restrict__ Wpack) {
    int gid = blockIdx.x * 256 + threadIdx.x;
    if (gid >= 1114112) return;
    int j = gid & 7;
    int l = (gid >> 3) & 63;
    int kpart = (l >> 4) * 8 + j;
    int npart = l & 15;
    float v;
    if (gid < 786432) {
        int f = gid >> 9;
        int s = f % 3;
        int rem = f / 3;
        int kb = rem & 15, ct = rem >> 4;
        int k = kb * 32 + kpart;
        int c = ct * 16 + npart;
        if (s == 0)      v = W_gd[(size_t)(D_ + k) * 1024 + c];
        else if (s == 1) v = W_gd[(size_t)(D_ + k) * 1024 + 512 + c];
        else             v = W_tau[(size_t)k * 512 + c];
    } else if (gid < 851968) {
        int r = gid - 786432;
        int f = r >> 9;
        int s = f & 1, kb = (f >> 1) & 1, ct = f >> 2;
        int k = kb * 32 + kpart;
        int c = ct * 16 + npart;
        v = W_gd[(size_t)k * 1024 + s * 512 + c];
    } else if (gid < 983040) {
        int r = gid - 851968;
        int f = r >> 9;
        int s = f & 1, kb = (f >> 1) & 3, ct = f >> 3;
        int k = kb * 32 + kpart;
        int c = ct * 16 + npart;
        v = W_gd[(size_t)(D_ + H_ + k) * 1024 + s * 512 + c];
    } else {
        int r = gid - 983040;
        int f = r >> 9;
        int kb = f & 15, c4 = f >> 4;
        int k = kb * 32 + kpart;
        int n = (c4 & 7) * 16 + npart;
        v = (c4 < 8) ? Wk[(size_t)k * A_ + n] : Wv[(size_t)k * A_ + n];
    }
    Wpack[gid] = f2bf_(v);
}

// ---- group barrier: 8 blocks, per-block flag slots (scope-templated) -------
template <bool FAST>
__device__ __forceinline__ void gsyncT(unsigned* flags, int j, unsigned cnt) {
    asm volatile("s_waitcnt vmcnt(0)" ::: "memory");  // drain data stores
    __syncthreads();
    if (threadIdx.x == 0) stu32x<FAST>(flags + j * 64, cnt);
    if (threadIdx.x < 8) {
        while (ldu32x<FAST>(flags + (int)threadIdx.x * 64) < cnt) {
            __builtin_amdgcn_s_sleep(1);
        }
    }
    __syncthreads();
}

struct P {
    const float *x, *dts, *Wq, *bq, *bk, *bv, *b_gd, *b_tau, *gleak, *cm,
        *W_fc, *b_fc;
    float *h, *ctx, *out, *Kpart, *Vpart;
    unsigned short* Kh;  // K: [B][T][A] bf16 (block-private rows, plain ld/st)
    const unsigned short *Wy, *Wx, *Wc, *Wkv;
    unsigned short *hpack, *yapack, *ybpack;  // layout [m_tile][strip][row][col]
    unsigned* bar;
};

struct Shm {
    float WqL[D_ * 129];
    float xs4[2][D_];
    float q4[2][A_];
    float sc4[2][T_];
    float red[2][2];
    alignas(16) unsigned short AsL[32 * 256];  // 16 KB staged A
    alignas(16) unsigned short ypbuf[4 * 256]; // 2 KB transpose
    alignas(16) unsigned short As2[2 * 512];   // kv h A-frags
    unsigned short VhL[2][A_][136];            // ~70 KB V history
    unsigned xcs[8];                           // handshake scratch
    int gj[3];                                 // dynamic g, j, roster-ok
};

template <bool FAST>
__device__ __forceinline__ void run_body(const P& p, Shm& sh, const int g,
                                         const int j) {
    const int tid = threadIdx.x;
    const int lane = tid & 63;
    const int wave = tid >> 6;            // 0..3
    const int ct = j * 4 + wave;          // channel strip 0..31
    unsigned* flags = p.bar + g * 512;
    unsigned cnt = 0;

    const int quad = lane >> 4;
    const int c = ct * 16 + (lane & 15);
    const float btau = p.b_tau[c];
    const float lk = sp_(p.cm[c]) + sp_(p.gleak[c]) + 1e-6f;
    const float bgd_g = p.b_gd[c];
    const float bgd_d = p.b_gd[512 + c];
    const int aoff = (quad >> 1) * 256 + (lane & 15) * 16 + (quad & 1) * 8;
    const int ypw = wave * 256 + (lane & 15);

    const int sub = tid >> 7;             // 0..1
    const int tl = tid & 127;
    const int r = g * 16 + j * 2 + sub;   // this block's 2 attention rows
    const int rrow = r & 15;

    // ---- persistent register weights: 60 frags (240 VGPRs) ----
    short8 wg[16], wd[16], wt[16];
    short8 wxg[2], wxd[2], wcg[4], wcd[4];
    {
        const short8* Wy8 = (const short8*)p.Wy;
        #pragma unroll
        for (int kb = 0; kb < 16; ++kb) {
            wg[kb] = Wy8[((ct * 16 + kb) * 3 + 0) * 64 + lane];
            wd[kb] = Wy8[((ct * 16 + kb) * 3 + 1) * 64 + lane];
            wt[kb] = Wy8[((ct * 16 + kb) * 3 + 2) * 64 + lane];
        }
        const short8* Wx8 = (const short8*)p.Wx;
        const short8* Wc8 = (const short8*)p.Wc;
        #pragma unroll
        for (int kb = 0; kb < 2; ++kb) {
            wxg[kb] = Wx8[((ct * 2 + kb) * 2 + 0) * 64 + lane];
            wxd[kb] = Wx8[((ct * 2 + kb) * 2 + 1) * 64 + lane];
        }
        #pragma unroll
        for (int kb = 0; kb < 4; ++kb) {
            wcg[kb] = Wc8[((ct * 4 + kb) * 2 + 0) * 64 + lane];
            wcd[kb] = Wc8[((ct * 4 + kb) * 2 + 1) * 64 + lane];
        }
    }

    for (int i = tid; i < D_ * A_; i += 256) {
        int d = i >> 7, a = i & 127;
        sh.WqL[d * 129 + a] = p.Wq[i];
    }

    floatx4 hreg = {0.f, 0.f, 0.f, 0.f};
    floatx4 rk1, rk2, rk3, baseg, based, ycur, dt4;

    const short8* Wkv8 = (const short8*)p.Wkv;

    __syncthreads();  // WqL ready

    for (int t = 0; t < T_; ++t) {
        // ---------- phase A: K/V merge of t-1 + attention (2 rows) ----------
        {
            if (t > 0) {
                // batched: issue all 16 loads, one waitcnt, then sum
                float kk[8], vv[8];
                #pragma unroll
                for (int jj = 0; jj < 8; ++jj) {
                    ld4x<FAST>(kk[jj],
                               p.Kpart + ((g * 8 + jj) * 16 + rrow) * 128 + tl);
                    ld4x<FAST>(vv[jj],
                               p.Vpart + ((g * 8 + jj) * 16 + rrow) * 128 + tl);
                }
                vmwait16f(kk[0], kk[1], kk[2], kk[3], kk[4], kk[5], kk[6],
                          kk[7], vv[0], vv[1], vv[2], vv[3], vv[4], vv[5],
                          vv[6], vv[7]);
                float ks = p.bk[tl], vs = p.bv[tl];
                #pragma unroll
                for (int jj = 0; jj < 8; ++jj) {
                    ks += kk[jj];
                    vs += vv[jj];
                }
                p.Kh[(size_t)(r * T_ + (t - 1)) * A_ + tl] = f2bf_(ks);
                sh.VhL[sub][tl][t - 1] = f2bf_(vs);
            }
            if (tl < 16)
                ((float4*)sh.xs4[sub])[tl] =
                    ((const float4*)&p.x[(r * T_ + t) * D_])[tl];
            __syncthreads();
            float qa = p.bq[tl];
            #pragma unroll 8
            for (int d = 0; d < D_; ++d)
                qa += sh.xs4[sub][d] * sh.WqL[d * 129 + tl];
            sh.q4[sub][tl] = qa;
            __syncthreads();
            if (t == 0) {
                stfx<FAST>(p.ctx + r * A_ + tl, 0.f);
            } else {
                const float rscale = 0.08838834764831845f;  // 1/sqrt(128)
                const int grp = tl >> 4, ln = tl & 15;
                float qv[8];
                #pragma unroll
                for (int i = 0; i < 8; ++i) qv[i] = sh.q4[sub][ln * 8 + i];
                for (int s = grp; s < t; s += 8) {
                    ushort8 k8 = *((const ushort8*)(p.Kh +
                                     (size_t)(r * T_ + s) * A_) + ln);
                    float a2 = 0.f;
                    #pragma unroll
                    for (int i = 0; i < 8; ++i) a2 += bf2f_(k8[i]) * qv[i];
                    #pragma unroll
                    for (int off = 8; off > 0; off >>= 1)
                        a2 += __shfl_xor(a2, off, 16);
                    if (ln == 0) sh.sc4[sub][s] = a2 * rscale;
                }
                __syncthreads();
                float mloc = -1e30f;
                for (int s = tl; s < t; s += 128)
                    mloc = fmaxf(mloc, sh.sc4[sub][s]);
                #pragma unroll
                for (int off = 32; off > 0; off >>= 1)
                    mloc = fmaxf(mloc, __shfl_xor(mloc, off, 64));
                if (lane == 0) sh.red[sub][wave & 1] = mloc;
                __syncthreads();
                float m = fmaxf(sh.red[sub][0], sh.red[sub][1]);
                float ssum = 0.f;
                for (int s = tl; s < t; s += 128) {
                    float e = expf(sh.sc4[sub][s] - m);
                    sh.sc4[sub][s] = e;
                    ssum += e;
                }
                #pragma unroll
                for (int off = 32; off > 0; off >>= 1)
                    ssum += __shfl_xor(ssum, off, 64);
                __syncthreads();
                if (lane == 0) sh.red[sub][wave & 1] = ssum;
                __syncthreads();
                float rs = 1.f / (sh.red[sub][0] + sh.red[sub][1]);
                const unsigned short* Vrow = &sh.VhL[sub][tl][0];
                float ca0 = 0.f, ca1 = 0.f;
                int s0 = 0;
                for (; s0 + 16 <= t; s0 += 16) {
                    ushort8 v0 = *(const ushort8*)(Vrow + s0);
                    ushort8 v1 = *(const ushort8*)(Vrow + s0 + 8);
                    #pragma unroll
                    for (int i = 0; i < 8; ++i) {
                        ca0 += sh.sc4[sub][s0 + i] * bf2f_(v0[i]);
                        ca1 += sh.sc4[sub][s0 + 8 + i] * bf2f_(v1[i]);
                    }
                }
                if (s0 + 8 <= t) {
                    ushort8 v0 = *(const ushort8*)(Vrow + s0);
                    #pragma unroll
                    for (int i = 0; i < 8; ++i)
                        ca0 += sh.sc4[sub][s0 + i] * bf2f_(v0[i]);
                    s0 += 8;
                }
                for (; s0 < t; ++s0) ca0 += sh.sc4[sub][s0] * bf2f_(Vrow[s0]);
                stfx<FAST>(p.ctx + r * A_ + tl, (ca0 + ca1) * rs);
            }
        }
        gsyncT<FAST>(flags, j, ++cnt);

        // ---------- phase B: stage1 + base fold (register weights) ----------
        {
            // stage m_tile's hpack (16 KB) -> LDS: 4 batched 16B loads
            {
                const unsigned short* src = p.hpack + g * 8192;
                uintx4 av[4];
                #pragma unroll
                for (int i = 0; i < 4; ++i)
                    ld16x<FAST>(av[i], src + (size_t)tid * 8 + i * 2048);
                vmwait4(av[0], av[1], av[2], av[3]);
                #pragma unroll
                for (int i = 0; i < 4; ++i)
                    ((uintx4*)sh.AsL)[tid + i * 256] = av[i];
            }
            // ctx row: 8 batched 16B loads
            const int mrow = lane & 15;
            const int kq = lane >> 4;
            const float* crow = &p.ctx[(g * 16 + mrow) * A_];
            uintx4 cc[8];
            #pragma unroll
            for (int kb = 0; kb < 4; ++kb) {
                ld16x<FAST>(cc[2 * kb], crow + kb * 32 + kq * 8);
                ld16x<FAST>(cc[2 * kb + 1], crow + kb * 32 + kq * 8 + 4);
            }
            vmwait8(cc[0], cc[1], cc[2], cc[3], cc[4], cc[5], cc[6], cc[7]);
            __syncthreads();  // AsL ready

            #pragma unroll
            for (int i = 0; i < 4; ++i)
                dt4[i] = p.dts[(g * 16 + quad * 4 + i) * T_ + t];

            floatx4 bg = {0.f, 0.f, 0.f, 0.f};
            floatx4 bd = {0.f, 0.f, 0.f, 0.f};
            const float4* xrow =
                (const float4*)&p.x[((g * 16 + mrow) * T_ + t) * D_];
            #pragma unroll
            for (int kb = 0; kb < 2; ++kb) {
                float4 u = xrow[kb * 8 + kq * 2], v = xrow[kb * 8 + kq * 2 + 1];
                short8 ax;
                ax[0] = (short)f2bf_(u.x); ax[1] = (short)f2bf_(u.y);
                ax[2] = (short)f2bf_(u.z); ax[3] = (short)f2bf_(u.w);
                ax[4] = (short)f2bf_(v.x); ax[5] = (short)f2bf_(v.y);
                ax[6] = (short)f2bf_(v.z); ax[7] = (short)f2bf_(v.w);
                bg = __builtin_amdgcn_mfma_f32_16x16x32_bf16(ax, wxg[kb], bg, 0, 0, 0);
                bd = __builtin_amdgcn_mfma_f32_16x16x32_bf16(ax, wxd[kb], bd, 0, 0, 0);
            }
            #pragma unroll
            for (int kb = 0; kb < 4; ++kb) {
                floatx4 f0 = u2f_(cc[2 * kb]), f1 = u2f_(cc[2 * kb + 1]);
                short8 ac;
                ac[0] = (short)f2bf_(f0[0]); ac[1] = (short)f2bf_(f0[1]);
                ac[2] = (short)f2bf_(f0[2]); ac[3] = (short)f2bf_(f0[3]);
                ac[4] = (short)f2bf_(f1[0]); ac[5] = (short)f2bf_(f1[1]);
                ac[6] = (short)f2bf_(f1[2]); ac[7] = (short)f2bf_(f1[3]);
                bg = __builtin_amdgcn_mfma_f32_16x16x32_bf16(ac, wcg[kb], bg, 0, 0, 0);
                bd = __builtin_amdgcn_mfma_f32_16x16x32_bf16(ac, wcd[kb], bd, 0, 0, 0);
            }
            floatx4 ag = {0.f, 0.f, 0.f, 0.f};
            floatx4 ad = {0.f, 0.f, 0.f, 0.f};
            floatx4 at = {0.f, 0.f, 0.f, 0.f};
            #pragma unroll
            for (int kb = 0; kb < 16; ++kb) {
                short8 a = *(const short8*)(sh.AsL + kb * 512 + aoff);
                ag = __builtin_amdgcn_mfma_f32_16x16x32_bf16(a, wg[kb], ag, 0, 0, 0);
                ad = __builtin_amdgcn_mfma_f32_16x16x32_bf16(a, wd[kb], ad, 0, 0, 0);
                at = __builtin_amdgcn_mfma_f32_16x16x32_bf16(a, wt[kb], at, 0, 0, 0);
            }
            #pragma unroll
            for (int i = 0; i < 4; ++i) {
                baseg[i] = bg[i] + bgd_g;
                based[i] = bd[i] + bgd_d;
                float gate = ag[i] + baseg[i];
                float dyn = ad[i] + based[i];
                float tau = sp_(at[i] + btau);
                float ki = (sigm_(gate) * tanhf(dyn) - hreg[i]) / (tau + lk);
                rk1[i] = ki;
                float yn = hreg[i] + dt4[i] * ki * (1.f / 3.f);
                ycur[i] = yn;
                sh.ypbuf[ypw + (quad * 4 + i) * 16] = f2bf_(yn);
            }
            __syncthreads();
            st64x<FAST>((ull*)p.yapack + g * 2048 + j * 256 + tid,
                        ((const ull*)sh.ypbuf)[tid]);
        }
        gsyncT<FAST>(flags, j, ++cnt);

        // ---------- stages 2..4 ----------
        #pragma unroll 1
        for (int stage = 2; stage <= 4; ++stage) {
            const unsigned short* ysrc =
                (stage == 2) ? p.yapack : (stage == 3) ? p.ybpack : p.yapack;
            unsigned short* ydst =
                (stage == 2) ? p.ybpack : (stage == 3) ? p.yapack : p.hpack;
            {
                const unsigned short* src = ysrc + g * 8192;
                uintx4 av[4];
                #pragma unroll
                for (int i = 0; i < 4; ++i)
                    ld16x<FAST>(av[i], src + (size_t)tid * 8 + i * 2048);
                vmwait4(av[0], av[1], av[2], av[3]);
                #pragma unroll
                for (int i = 0; i < 4; ++i)
                    ((uintx4*)sh.AsL)[tid + i * 256] = av[i];
            }
            __syncthreads();
            floatx4 ag = {0.f, 0.f, 0.f, 0.f};
            floatx4 ad = {0.f, 0.f, 0.f, 0.f};
            floatx4 at = {0.f, 0.f, 0.f, 0.f};
            #pragma unroll
            for (int kb = 0; kb < 16; ++kb) {
                short8 a = *(const short8*)(sh.AsL + kb * 512 + aoff);
                ag = __builtin_amdgcn_mfma_f32_16x16x32_bf16(a, wg[kb], ag, 0, 0, 0);
                ad = __builtin_amdgcn_mfma_f32_16x16x32_bf16(a, wd[kb], ad, 0, 0, 0);
                at = __builtin_amdgcn_mfma_f32_16x16x32_bf16(a, wt[kb], at, 0, 0, 0);
            }
            const int lane_p = ((c >> 3) & 3) * 16;
            #pragma unroll
            for (int i = 0; i < 4; ++i) {
                float gate = ag[i] + baseg[i];
                float dyn = ad[i] + based[i];
                float tau = sp_(at[i] + btau);
                float ki = (sigm_(gate) * tanhf(dyn) - ycur[i]) / (tau + lk);
                float yn;
                if (stage == 2) {
                    rk2[i] = ki;
                    yn = hreg[i] + dt4[i] * (ki - rk1[i] * (1.f / 3.f));
                } else if (stage == 3) {
                    rk3[i] = ki;
                    yn = hreg[i] + dt4[i] * (rk1[i] - rk2[i] + ki);
                } else {
                    yn = hreg[i] +
                         dt4[i] * (rk1[i] + 3.f * rk2[i] + 3.f * rk3[i] + ki) * 0.125f;
                    hreg[i] = yn;
                }
                ycur[i] = yn;
                sh.ypbuf[ypw + (quad * 4 + i) * 16] = f2bf_(yn);
                if (stage == 4)
                    sh.As2[(wave >> 1) * 512 + (c & 7) +
                           (lane_p + quad * 4 + i) * 8] = f2bf_(yn);
            }
            __syncthreads();
            st64x<FAST>((ull*)ydst + g * 2048 + j * 256 + tid,
                        ((const ull*)sh.ypbuf)[tid]);
            if (stage == 4) {
                #pragma unroll
                for (int h4 = 0; h4 < 4; ++h4) {
                    const int c4 = wave + h4 * 4;  // 0..15 (0..7=K, 8..15=V)
                    floatx4 acc = {0.f, 0.f, 0.f, 0.f};
                    #pragma unroll
                    for (int kk2 = 0; kk2 < 2; ++kk2) {
                        short8 a = *(const short8*)(sh.As2 + (kk2 * 64 + lane) * 8);
                        acc = __builtin_amdgcn_mfma_f32_16x16x32_bf16(
                            a, Wkv8[(c4 * 16 + (j * 2 + kk2)) * 64 + lane], acc,
                            0, 0, 0);
                    }
                    const int ac = (c4 & 7) * 16 + (lane & 15);
                    float* part = (c4 < 8) ? p.Kpart : p.Vpart;
                    #pragma unroll
                    for (int i = 0; i < 4; ++i)
                        stfx<FAST>(part +
                                       ((g * 8 + j) * 16 + quad * 4 + i) * 128 +
                                       ac,
                                   acc[i]);
                }
            }
            gsyncT<FAST>(flags, j, ++cnt);
        }
    }

    // ---------- write final h, then fc ----------
    #pragma unroll
    for (int i = 0; i < 4; ++i)
        stfx<FAST>(p.h + (g * 16 + quad * 4 + i) * H_ + c, hreg[i]);
    gsyncT<FAST>(flags, j, ++cnt);
    {
        const int o = tl & 31, ks = tl >> 5;  // ks 0..3
        float acc = 0.f;
        const float* hrow = p.h + r * H_ + ks * 128;
        const float* wcol = p.W_fc + ks * 128 * O_ + o;
        #pragma unroll 1
        for (int rd = 0; rd < 4; ++rd) {
            uintx4 hh[8];
            #pragma unroll
            for (int i = 0; i < 8; ++i)
                ld16x<FAST>(hh[i], hrow + rd * 32 + i * 4);
            vmwait8(hh[0], hh[1], hh[2], hh[3], hh[4], hh[5], hh[6], hh[7]);
            #pragma unroll
            for (int i = 0; i < 8; ++i) {
                floatx4 f = u2f_(hh[i]);
                #pragma unroll
                for (int e = 0; e < 4; ++e)
                    acc += f[e] * wcol[(rd * 32 + i * 4 + e) * O_];
            }
        }
        sh.sc4[sub][tl] = acc;
        __syncthreads();
        if (ks == 0)
            p.out[r * O_ + o] = acc + sh.sc4[sub][o + 32] + sh.sc4[sub][o + 64] +
                                sh.sc4[sub][o + 96] + p.b_fc[o];
    }
}

__global__ __launch_bounds__(256, 1) void fused_kernel(P p) {
    __shared__ Shm sh;
    const int tid = threadIdx.x;
    const int bid = blockIdx.x;
    unsigned* xtra = p.bar + 8192;  // roster[0..7], arrive[8], yes[9], voted[10]

    // ---- R15 handshake: DISCOVER placement; every wait bounded or provably
    // terminating; mapping choice provably uniform across all 128 blocks.
    //
    // Phase 0 (roster): block reads physical XCC_ID, takes a rank on its
    //   XCD's roster (device-scope atomics, cross-XCD coherent), bumps the
    //   arrival counter, then BOUNDED-polls for all 128 arrivals.
    //   localok = arrived AND every XCD hosts exactly 16 blocks.
    // Phase 1 (vote, uniform by construction): every block votes localok and
    //   bumps the voted counter; poll until voted==128. This terminates iff
    //   every block executes — the same liveness the main loop's group
    //   barrier already requires (held for all of R0-R13). dynamic mapping
    //   is adopted iff ALL 128 voted yes -> no mixed-mapping state exists.
    //   g = xcd*2 + rank/8, j = rank%8 (bijection; work partition symmetric,
    //   so any bijection is correct). Groups are same-XCD BY CONSTRUCTION.
    // Phase 2 (probe+trial, bounded): sc0-only visibility check within the
    //   group through the exact main-loop path. Slots +32/+33 are on a line
    //   only ever touched sc0-only.
    // Phase 3 (verdict): per-group unanimous AND via the always-correct MALL
    //   path (every block stores -> poll terminates). All cross-block traffic
    //   is intra-group, so per-group fast/slow choice is safe.
    if (tid == 0) {
        unsigned myxcc;
        asm volatile("s_getreg_b32 %0, hwreg(HW_REG_XCC_ID)" : "=s"(myxcc));
        myxcc &= 7u;
        unsigned rank = atomicAdd(&xtra[myxcc], 1u);
        atomicAdd(&xtra[8], 1u);
        unsigned seen = 0;
        for (int it = 0; it < 16384; ++it) {
            seen = ldu32x<false>(&xtra[8]);
            if (seen >= 128u) break;
            __builtin_amdgcn_s_sleep(2);
        }
        bool localok = (seen >= 128u) && (rank < 16u);
        if (localok) {
            #pragma unroll
            for (int i = 0; i < 8; ++i)
                localok = localok && (ldu32x<false>(&xtra[i]) == 16u);
        }
        atomicAdd(&xtra[9], localok ? 1u : 0u);
        atomicAdd(&xtra[10], 1u);
        while (ldu32x<false>(&xtra[10]) < 128u) __builtin_amdgcn_s_sleep(1);
        bool dynok = (ldu32x<false>(&xtra[9]) == 128u);
        if (dynok) {
            sh.gj[0] = (int)(myxcc * 2u + (rank >> 3));
            sh.gj[1] = (int)(rank & 7u);
            sh.gj[2] = 1;
        } else {
            sh.gj[0] = bid & 15;
            sh.gj[1] = bid >> 4;
            sh.gj[2] = 0;
        }
    }
    __syncthreads();
    const int g = sh.gj[0];
    const int j = sh.gj[1];
    const bool rosterok = sh.gj[2] != 0;
    unsigned* flags = p.bar + g * 512;

    bool fast = false;
    if (rosterok) {
        // Probe: bounded sc0-only visibility check within the same-XCD group.
        if (tid == 0) stu32x<true>(flags + j * 64 + 32, 1u);
        if (tid < 8) {
            unsigned v = 0;
            for (int it = 0; it < 2048; ++it) {
                v = ldu32x<true>(flags + tid * 64 + 32);
                if (v) break;
                __builtin_amdgcn_s_sleep(2);
            }
            sh.xcs[tid] = v ? 1u : 0u;
        }
        __syncthreads();
        bool ok8 = true;
        #pragma unroll
        for (int i = 0; i < 8; ++i) ok8 = ok8 && (sh.xcs[i] != 0u);
        __syncthreads();

        // Trial: one more bounded barrier round through the exact main-loop
        // mechanism. Probe-failed blocks never store -> participants time
        // out -> unanimous fail below.
        bool trial_ok = false;
        if (ok8) {
            if (tid == 0) stu32x<true>(flags + j * 64 + 33, 1u);
            if (tid < 8) {
                unsigned v = 0;
                for (int it = 0; it < 2048; ++it) {
                    v = ldu32x<true>(flags + tid * 64 + 33);
                    if (v) break;
                    __builtin_amdgcn_s_sleep(2);
                }
                sh.xcs[tid] = v ? 1u : 0u;
            }
            __syncthreads();
            trial_ok = true;
            #pragma unroll
            for (int i = 0; i < 8; ++i)
                trial_ok = trial_ok && (sh.xcs[i] != 0u);
            __syncthreads();
        }

        // Verdict: unanimous AND over the always-correct MALL path. Every
        // block stores -> the poll always terminates.
        if (tid == 0) stu32x<false>(flags + j * 64 + 1, trial_ok ? 2u : 1u);
        if (tid < 8) {
            unsigned v;
            while ((v = ldu32x<false>(flags + tid * 64 + 1)) == 0u)
                __builtin_amdgcn_s_sleep(1);
            sh.xcs[tid] = (v == 2u) ? 1u : 0u;
        }
        __syncthreads();
        fast = true;
        #pragma unroll
        for (int i = 0; i < 8; ++i) fast = fast && (sh.xcs[i] != 0u);
    }

    if (fast)
        run_body<true>(p, sh, g, j);   // XCD-L2 exchange (~200 cy round trips)
    else
        run_body<false>(p, sh, g, j);  // MALL exchange (R11 behavior)
}

extern "C" void kernel_launch(void* const* d_in, const int* in_sizes, int n_in,
                              void* d_out, int out_size, void* d_ws,
                              size_t ws_size, hipStream_t stream) {
    (void)in_sizes; (void)n_in; (void)out_size; (void)ws_size;
    P p;
    p.x = (const float*)d_in[0];
    p.dts = (const float*)d_in[1];
    p.Wq = (const float*)d_in[2];
    p.bq = (const float*)d_in[3];
    const float* Wk = (const float*)d_in[4];
    p.bk = (const float*)d_in[5];
    const float* Wv = (const float*)d_in[6];
    p.bv = (const float*)d_in[7];
    const float* W_gd = (const float*)d_in[8];
    p.b_gd = (const float*)d_in[9];
    const float* W_tau = (const float*)d_in[10];
    p.b_tau = (const float*)d_in[11];
    p.gleak = (const float*)d_in[12];
    p.cm = (const float*)d_in[13];
    p.W_fc = (const float*)d_in[14];
    p.b_fc = (const float*)d_in[15];
    p.out = (float*)d_out;

    float* ws = (float*)d_ws;
    p.h = ws;                            // B*H fp32
    p.ctx = p.h + B_ * H_;               // B*A fp32
    p.Kpart = p.ctx + B_ * A_;           // 128*16*128 fp32
    p.Vpart = p.Kpart + 262144;
    unsigned short* Wpack = (unsigned short*)(p.Vpart + 262144);
    p.Wy = Wpack;                        // 786432 ushorts
    p.Wx = Wpack + 786432;               // 65536
    p.Wc = Wpack + 851968;               // 131072
    p.Wkv = Wpack + 983040;              // 131072
    p.hpack = Wpack + 1114112;           // B*H ushorts, strip-tile layout
    p.yapack = p.hpack + B_ * H_;
    p.ybpack = p.yapack + B_ * H_;
    p.Kh = p.ybpack + B_ * H_;           // B*T*A bf16 (block-private rows)
    p.bar = (unsigned*)(p.Kh + (size_t)B_ * T_ * A_);  // 8192+64 uints

    init_kernel<<<512, 256, 0, stream>>>(p.hpack, p.bar);
    pack_w_kernel<<<4352, 256, 0, stream>>>(W_gd, W_tau, Wk, Wv, Wpack);

    // 128 blocks x 256 threads, launch_bounds(256,1). R11: batched raw
    // `global_load sc0 sc1` + single operand-tied waitcnt removed per-load
    // serial MALL round trips. R13 post-mortem: bid%8 does NOT co-locate a
    // group on one XCD here (probe timeout +900us, WRITE_SIZE unchanged).
    // R14/R15: groups are built from MEASURED XCC_IDs via device-scope
    // atomics -> same-XCD by construction; bounded sc0 probe+trial verify
    // the L2-visibility mechanism; per-group unanimous verdict via MALL.
    // R15 hardening: arrival wait bounded + global unanimous vote so the
    // mapping choice is uniform in every outcome; all new waits terminate
    // under the same liveness the baseline group barrier already requires.
    fused_kernel<<<dim3(128), dim3(256), 0, stream>>>(p);
}

// Round 5
// 3587.967 us; speedup vs baseline: 1.2534x; 1.0477x over previous
//
#include <hip/hip_runtime.h>
#include <math.h>

#define B_ 256
#define T_ 128
#define D_ 64
#define H_ 512
#define A_ 128
#define O_ 32

typedef __attribute__((ext_vector_type(8))) short short8;
typedef __attribute__((ext_vector_type(8))) unsigned short ushort8;
typedef __attribute__((ext_vector_type(4))) float floatx4;
typedef __attribute__((ext_vector_type(4))) unsigned int uintx4;
typedef unsigned long long ull;

__device__ __forceinline__ float sp_(float x) {
    return fmaxf(x, 0.f) + log1pf(expf(-fabsf(x)));
}
__device__ __forceinline__ float sigm_(float x) {
    return 1.f / (1.f + expf(-x));
}
__device__ __forceinline__ unsigned short f2bf_(float f) {
    unsigned int u = __float_as_uint(f);
    return (unsigned short)((u + 0x7FFFu + ((u >> 16) & 1u)) >> 16);
}
__device__ __forceinline__ float bf2f_(unsigned short u) {
    return __uint_as_float(((unsigned)u) << 16);
}

// ---- scope-templated raw loads/stores --------------------------------------
// FAST=true  -> sc0 only: L1-bypass, serviced by the XCD-shared L2 (~200 cy).
//               Only taken when the group's 8 blocks are same-XCD BY
//               CONSTRUCTION (prefix-sum roster over measured XCC_IDs) AND a
//               bounded probe+trial through this exact path succeeded, with
//               the verdict AND-reduced over the always-correct sc0 sc1 path.
// FAST=false -> sc0 sc1: MALL-serviced (~900 cy). Always safe (R11 behavior).
template <bool FAST>
__device__ __forceinline__ void ld16x(uintx4& d, const void* p) {
    if constexpr (FAST)
        asm volatile("global_load_dwordx4 %0, %1, off sc0"
                     : "=v"(d) : "v"(p) : "memory");
    else
        asm volatile("global_load_dwordx4 %0, %1, off sc0 sc1"
                     : "=v"(d) : "v"(p) : "memory");
}
template <bool FAST>
__device__ __forceinline__ void ld4x(float& d, const void* p) {
    if constexpr (FAST)
        asm volatile("global_load_dword %0, %1, off sc0"
                     : "=v"(d) : "v"(p) : "memory");
    else
        asm volatile("global_load_dword %0, %1, off sc0 sc1"
                     : "=v"(d) : "v"(p) : "memory");
}
template <bool FAST>
__device__ __forceinline__ unsigned ldu32x(const unsigned* p) {
    unsigned d;
    if constexpr (FAST)
        asm volatile("global_load_dword %0, %1, off sc0\n\t"
                     "s_waitcnt vmcnt(0)"
                     : "=v"(d) : "v"(p) : "memory");
    else
        asm volatile("global_load_dword %0, %1, off sc0 sc1\n\t"
                     "s_waitcnt vmcnt(0)"
                     : "=v"(d) : "v"(p) : "memory");
    return d;
}
template <bool FAST>
__device__ __forceinline__ void stfx(float* p, float v) {
    if constexpr (FAST)
        asm volatile("global_store_dword %0, %1, off sc0"
                     :: "v"(p), "v"(v) : "memory");
    else
        asm volatile("global_store_dword %0, %1, off sc0 sc1"
                     :: "v"(p), "v"(v) : "memory");
}
template <bool FAST>
__device__ __forceinline__ void st64x(ull* p, ull v) {
    if constexpr (FAST)
        asm volatile("global_store_dwordx2 %0, %1, off sc0"
                     :: "v"(p), "v"(v) : "memory");
    else
        asm volatile("global_store_dwordx2 %0, %1, off sc0 sc1"
                     :: "v"(p), "v"(v) : "memory");
}
template <bool FAST>
__device__ __forceinline__ void stu32x(unsigned* p, unsigned v) {
    if constexpr (FAST)
        asm volatile("global_store_dword %0, %1, off sc0"
                     :: "v"(p), "v"(v) : "memory");
    else
        asm volatile("global_store_dword %0, %1, off sc0 sc1"
                     :: "v"(p), "v"(v) : "memory");
}

__device__ __forceinline__ void vmwait4(uintx4& a, uintx4& b, uintx4& c,
                                        uintx4& d) {
    asm volatile("s_waitcnt vmcnt(0)"
                 : "+v"(a), "+v"(b), "+v"(c), "+v"(d)::"memory");
}
__device__ __forceinline__ void vmwait8(uintx4& a, uintx4& b, uintx4& c,
                                        uintx4& d, uintx4& e, uintx4& f,
                                        uintx4& g, uintx4& h) {
    asm volatile("s_waitcnt vmcnt(0)"
                 : "+v"(a), "+v"(b), "+v"(c), "+v"(d), "+v"(e), "+v"(f),
                   "+v"(g), "+v"(h)::"memory");
}
__device__ __forceinline__ void vmwait16f(float& a0, float& a1, float& a2,
                                          float& a3, float& a4, float& a5,
                                          float& a6, float& a7, float& b0,
                                          float& b1, float& b2, float& b3,
                                          float& b4, float& b5, float& b6,
                                          float& b7) {
    asm volatile("s_waitcnt vmcnt(0)"
                 : "+v"(a0), "+v"(a1), "+v"(a2), "+v"(a3), "+v"(a4), "+v"(a5),
                   "+v"(a6), "+v"(a7), "+v"(b0), "+v"(b1), "+v"(b2), "+v"(b3),
                   "+v"(b4), "+v"(b5), "+v"(b6), "+v"(b7)::"memory");
}
__device__ __forceinline__ floatx4 u2f_(uintx4 u) {
    union { uintx4 u; floatx4 f; } c;
    c.u = u;
    return c.f;
}

// ---------------- init: hpack = 0, flags+roster = 0 --------------------------
__global__ void init_kernel(unsigned short* __restrict__ hpack,
                            unsigned* __restrict__ bar) {
    int i = blockIdx.x * 256 + threadIdx.x;
    if (i < B_ * H_) hpack[i] = 0;
    if (i < 8192 + 64) bar[i] = 0u;   // flags + roster/vote scratch
}

// -------- pack all weights into MFMA B-frag bf16 order ----------------------
__global__ void pack_w_kernel(const float* __restrict__ W_gd,
                              const float* __restrict__ W_tau,
                              const float* __restrict__ Wk,
                              const float* __restrict__ Wv,
                              unsigned short* __restrict__ Wpack) {
    int gid = blockIdx.x * 256 + threadIdx.x;
    if (gid >= 1114112) return;
    int j = gid & 7;
    int l = (gid >> 3) & 63;
    int kpart = (l >> 4) * 8 + j;
    int npart = l & 15;
    float v;
    if (gid < 786432) {
        int f = gid >> 9;
        int s = f % 3;
        int rem = f / 3;
        int kb = rem & 15, ct = rem >> 4;
        int k = kb * 32 + kpart;
        int c = ct * 16 + npart;
        if (s == 0)      v = W_gd[(size_t)(D_ + k) * 1024 + c];
        else if (s == 1) v = W_gd[(size_t)(D_ + k) * 1024 + 512 + c];
        else             v = W_tau[(size_t)k * 512 + c];
    } else if (gid < 851968) {
        int r = gid - 786432;
        int f = r >> 9;
        int s = f & 1, kb = (f >> 1) & 1, ct = f >> 2;
        int k = kb * 32 + kpart;
        int c = ct * 16 + npart;
        v = W_gd[(size_t)k * 1024 + s * 512 + c];
    } else if (gid < 983040) {
        int r = gid - 851968;
        int f = r >> 9;
        int s = f & 1, kb = (f >> 1) & 3, ct = f >> 3;
        int k = kb * 32 + kpart;
        int c = ct * 16 + npart;
        v = W_gd[(size_t)(D_ + H_ + k) * 1024 + s * 512 + c];
    } else {
        int r = gid - 983040;
        int f = r >> 9;
        int kb = f & 15, c4 = f >> 4;
        int k = kb * 32 + kpart;
        int n = (c4 & 7) * 16 + npart;
        v = (c4 < 8) ? Wk[(size_t)k * A_ + n] : Wv[(size_t)k * A_ + n];
    }
    Wpack[gid] = f2bf_(v);
}

// ---- group barrier: 8 blocks, per-block flag slots (scope-templated) -------
template <bool FAST>
__device__ __forceinline__ void gsyncT(unsigned* flags, int j, unsigned cnt) {
    asm volatile("s_waitcnt vmcnt(0)" ::: "memory");  // drain data stores
    __syncthreads();
    if (threadIdx.x == 0) stu32x<FAST>(flags + j * 64, cnt);
    if (threadIdx.x < 8) {
        while (ldu32x<FAST>(flags + (int)threadIdx.x * 64) < cnt) {
            __builtin_amdgcn_s_sleep(1);
        }
    }
    __syncthreads();
}

struct P {
    const float *x, *dts, *Wq, *bq, *bk, *bv, *b_gd, *b_tau, *gleak, *cm,
        *W_fc, *b_fc;
    float *h, *ctx, *out, *Kpart, *Vpart;
    unsigned short* Kh;  // K: [B][T][A] bf16 (block-private rows, plain ld/st)
    const unsigned short *Wy, *Wx, *Wc, *Wkv;
    unsigned short *hpack, *yapack, *ybpack;  // layout [m_tile][strip][row][col]
    unsigned* bar;
};

struct Shm {
    float WqL[D_ * 129];
    float xs4[2][D_];
    float q4[2][A_];
    float sc4[2][T_];
    float red[2][2];
    alignas(16) unsigned short AsL[32 * 256];  // 16 KB staged A
    alignas(16) unsigned short ypbuf[4 * 256]; // 2 KB transpose
    alignas(16) unsigned short As2[2 * 512];   // kv h A-frags
    unsigned short VhL[2][A_][136];            // ~70 KB V history
    unsigned xcs[8];                           // handshake scratch
    int gj[3];                                 // dynamic g, j, roster-ok
};

template <bool FAST>
__device__ __forceinline__ void run_body(const P& p, Shm& sh, const int g,
                                         const int j) {
    const int tid = threadIdx.x;
    const int lane = tid & 63;
    const int wave = tid >> 6;            // 0..3
    const int ct = j * 4 + wave;          // channel strip 0..31
    unsigned* flags = p.bar + g * 512;
    unsigned cnt = 0;

    const int quad = lane >> 4;
    const int c = ct * 16 + (lane & 15);
    const float btau = p.b_tau[c];
    const float lk = sp_(p.cm[c]) + sp_(p.gleak[c]) + 1e-6f;
    const float bgd_g = p.b_gd[c];
    const float bgd_d = p.b_gd[512 + c];
    const int aoff = (quad >> 1) * 256 + (lane & 15) * 16 + (quad & 1) * 8;
    const int ypw = wave * 256 + (lane & 15);

    const int sub = tid >> 7;             // 0..1
    const int tl = tid & 127;
    const int r = g * 16 + j * 2 + sub;   // this block's 2 attention rows
    const int rrow = r & 15;

    // ---- persistent register weights: 60 frags (240 VGPRs) ----
    short8 wg[16], wd[16], wt[16];
    short8 wxg[2], wxd[2], wcg[4], wcd[4];
    {
        const short8* Wy8 = (const short8*)p.Wy;
        #pragma unroll
        for (int kb = 0; kb < 16; ++kb) {
            wg[kb] = Wy8[((ct * 16 + kb) * 3 + 0) * 64 + lane];
            wd[kb] = Wy8[((ct * 16 + kb) * 3 + 1) * 64 + lane];
            wt[kb] = Wy8[((ct * 16 + kb) * 3 + 2) * 64 + lane];
        }
        const short8* Wx8 = (const short8*)p.Wx;
        const short8* Wc8 = (const short8*)p.Wc;
        #pragma unroll
        for (int kb = 0; kb < 2; ++kb) {
            wxg[kb] = Wx8[((ct * 2 + kb) * 2 + 0) * 64 + lane];
            wxd[kb] = Wx8[((ct * 2 + kb) * 2 + 1) * 64 + lane];
        }
        #pragma unroll
        for (int kb = 0; kb < 4; ++kb) {
            wcg[kb] = Wc8[((ct * 4 + kb) * 2 + 0) * 64 + lane];
            wcd[kb] = Wc8[((ct * 4 + kb) * 2 + 1) * 64 + lane];
        }
    }

    for (int i = tid; i < D_ * A_; i += 256) {
        int d = i >> 7, a = i & 127;
        sh.WqL[d * 129 + a] = p.Wq[i];
    }

    floatx4 hreg = {0.f, 0.f, 0.f, 0.f};
    floatx4 rk1, rk2, rk3, baseg, based, ycur, dt4;

    const short8* Wkv8 = (const short8*)p.Wkv;

    __syncthreads();  // WqL ready

    for (int t = 0; t < T_; ++t) {
        // ---------- phase A: K/V merge of t-1 + attention (2 rows) ----------
        {
            if (t > 0) {
                // batched: issue all 16 loads, one waitcnt, then sum
                float kk[8], vv[8];
                #pragma unroll
                for (int jj = 0; jj < 8; ++jj) {
                    ld4x<FAST>(kk[jj],
                               p.Kpart + ((g * 8 + jj) * 16 + rrow) * 128 + tl);
                    ld4x<FAST>(vv[jj],
                               p.Vpart + ((g * 8 + jj) * 16 + rrow) * 128 + tl);
                }
                vmwait16f(kk[0], kk[1], kk[2], kk[3], kk[4], kk[5], kk[6],
                          kk[7], vv[0], vv[1], vv[2], vv[3], vv[4], vv[5],
                          vv[6], vv[7]);
                float ks = p.bk[tl], vs = p.bv[tl];
                #pragma unroll
                for (int jj = 0; jj < 8; ++jj) {
                    ks += kk[jj];
                    vs += vv[jj];
                }
                p.Kh[(size_t)(r * T_ + (t - 1)) * A_ + tl] = f2bf_(ks);
                sh.VhL[sub][tl][t - 1] = f2bf_(vs);
            }
            if (tl < 16)
                ((float4*)sh.xs4[sub])[tl] =
                    ((const float4*)&p.x[(r * T_ + t) * D_])[tl];
            __syncthreads();
            float qa = p.bq[tl];
            #pragma unroll 8
            for (int d = 0; d < D_; ++d)
                qa += sh.xs4[sub][d] * sh.WqL[d * 129 + tl];
            sh.q4[sub][tl] = qa;
            __syncthreads();
            if (t == 0) {
                stfx<FAST>(p.ctx + r * A_ + tl, 0.f);
            } else {
                const float rscale = 0.08838834764831845f;  // 1/sqrt(128)
                const int grp = tl >> 4, ln = tl & 15;
                float qv[8];
                #pragma unroll
                for (int i = 0; i < 8; ++i) qv[i] = sh.q4[sub][ln * 8 + i];
                for (int s = grp; s < t; s += 8) {
                    ushort8 k8 = *((const ushort8*)(p.Kh +
                                     (size_t)(r * T_ + s) * A_) + ln);
                    float a2 = 0.f;
                    #pragma unroll
                    for (int i = 0; i < 8; ++i) a2 += bf2f_(k8[i]) * qv[i];
                    #pragma unroll
                    for (int off = 8; off > 0; off >>= 1)
                        a2 += __shfl_xor(a2, off, 16);
                    if (ln == 0) sh.sc4[sub][s] = a2 * rscale;
                }
                __syncthreads();
                float mloc = -1e30f;
                for (int s = tl; s < t; s += 128)
                    mloc = fmaxf(mloc, sh.sc4[sub][s]);
                #pragma unroll
                for (int off = 32; off > 0; off >>= 1)
                    mloc = fmaxf(mloc, __shfl_xor(mloc, off, 64));
                if (lane == 0) sh.red[sub][wave & 1] = mloc;
                __syncthreads();
                float m = fmaxf(sh.red[sub][0], sh.red[sub][1]);
                float ssum = 0.f;
                for (int s = tl; s < t; s += 128) {
                    float e = expf(sh.sc4[sub][s] - m);
                    sh.sc4[sub][s] = e;
                    ssum += e;
                }
                #pragma unroll
                for (int off = 32; off > 0; off >>= 1)
                    ssum += __shfl_xor(ssum, off, 64);
                __syncthreads();
                if (lane == 0) sh.red[sub][wave & 1] = ssum;
                __syncthreads();
                float rs = 1.f / (sh.red[sub][0] + sh.red[sub][1]);
                const unsigned short* Vrow = &sh.VhL[sub][tl][0];
                float ca0 = 0.f, ca1 = 0.f;
                int s0 = 0;
                for (; s0 + 16 <= t; s0 += 16) {
                    ushort8 v0 = *(const ushort8*)(Vrow + s0);
                    ushort8 v1 = *(const ushort8*)(Vrow + s0 + 8);
                    #pragma unroll
                    for (int i = 0; i < 8; ++i) {
                        ca0 += sh.sc4[sub][s0 + i] * bf2f_(v0[i]);
                        ca1 += sh.sc4[sub][s0 + 8 + i] * bf2f_(v1[i]);
                    }
                }
                if (s0 + 8 <= t) {
                    ushort8 v0 = *(const ushort8*)(Vrow + s0);
                    #pragma unroll
                    for (int i = 0; i < 8; ++i)
                        ca0 += sh.sc4[sub][s0 + i] * bf2f_(v0[i]);
                    s0 += 8;
                }
                for (; s0 < t; ++s0) ca0 += sh.sc4[sub][s0] * bf2f_(Vrow[s0]);
                stfx<FAST>(p.ctx + r * A_ + tl, (ca0 + ca1) * rs);
            }
        }
        gsyncT<FAST>(flags, j, ++cnt);

        // ---------- phase B: stage1 + base fold (register weights) ----------
        {
            // stage m_tile's hpack (16 KB) -> LDS: 4 batched 16B loads
            {
                const unsigned short* src = p.hpack + g * 8192;
                uintx4 av[4];
                #pragma unroll
                for (int i = 0; i < 4; ++i)
                    ld16x<FAST>(av[i], src + (size_t)tid * 8 + i * 2048);
                vmwait4(av[0], av[1], av[2], av[3]);
                #pragma unroll
                for (int i = 0; i < 4; ++i)
                    ((uintx4*)sh.AsL)[tid + i * 256] = av[i];
            }
            // ctx row: 8 batched 16B loads
            const int mrow = lane & 15;
            const int kq = lane >> 4;
            const float* crow = &p.ctx[(g * 16 + mrow) * A_];
            uintx4 cc[8];
            #pragma unroll
            for (int kb = 0; kb < 4; ++kb) {
                ld16x<FAST>(cc[2 * kb], crow + kb * 32 + kq * 8);
                ld16x<FAST>(cc[2 * kb + 1], crow + kb * 32 + kq * 8 + 4);
            }
            vmwait8(cc[0], cc[1], cc[2], cc[3], cc[4], cc[5], cc[6], cc[7]);
            __syncthreads();  // AsL ready

            #pragma unroll
            for (int i = 0; i < 4; ++i)
                dt4[i] = p.dts[(g * 16 + quad * 4 + i) * T_ + t];

            floatx4 bg = {0.f, 0.f, 0.f, 0.f};
            floatx4 bd = {0.f, 0.f, 0.f, 0.f};
            const float4* xrow =
                (const float4*)&p.x[((g * 16 + mrow) * T_ + t) * D_];
            #pragma unroll
            for (int kb = 0; kb < 2; ++kb) {
                float4 u = xrow[kb * 8 + kq * 2], v = xrow[kb * 8 + kq * 2 + 1];
                short8 ax;
                ax[0] = (short)f2bf_(u.x); ax[1] = (short)f2bf_(u.y);
                ax[2] = (short)f2bf_(u.z); ax[3] = (short)f2bf_(u.w);
                ax[4] = (short)f2bf_(v.x); ax[5] = (short)f2bf_(v.y);
                ax[6] = (short)f2bf_(v.z); ax[7] = (short)f2bf_(v.w);
                bg = __builtin_amdgcn_mfma_f32_16x16x32_bf16(ax, wxg[kb], bg, 0, 0, 0);
                bd = __builtin_amdgcn_mfma_f32_16x16x32_bf16(ax, wxd[kb], bd, 0, 0, 0);
            }
            #pragma unroll
            for (int kb = 0; kb < 4; ++kb) {
                floatx4 f0 = u2f_(cc[2 * kb]), f1 = u2f_(cc[2 * kb + 1]);
                short8 ac;
                ac[0] = (short)f2bf_(f0[0]); ac[1] = (short)f2bf_(f0[1]);
                ac[2] = (short)f2bf_(f0[2]); ac[3] = (short)f2bf_(f0[3]);
                ac[4] = (short)f2bf_(f1[0]); ac[5] = (short)f2bf_(f1[1]);
                ac[6] = (short)f2bf_(f1[2]); ac[7] = (short)f2bf_(f1[3]);
                bg = __builtin_amdgcn_mfma_f32_16x16x32_bf16(ac, wcg[kb], bg, 0, 0, 0);
                bd = __builtin_amdgcn_mfma_f32_16x16x32_bf16(ac, wcd[kb], bd, 0, 0, 0);
            }
            floatx4 ag = {0.f, 0.f, 0.f, 0.f};
            floatx4 ad = {0.f, 0.f, 0.f, 0.f};
            floatx4 at = {0.f, 0.f, 0.f, 0.f};
            #pragma unroll
            for (int kb = 0; kb < 16; ++kb) {
                short8 a = *(const short8*)(sh.AsL + kb * 512 + aoff);
                ag = __builtin_amdgcn_mfma_f32_16x16x32_bf16(a, wg[kb], ag, 0, 0, 0);
                ad = __builtin_amdgcn_mfma_f32_16x16x32_bf16(a, wd[kb], ad, 0, 0, 0);
                at = __builtin_amdgcn_mfma_f32_16x16x32_bf16(a, wt[kb], at, 0, 0, 0);
            }
            #pragma unroll
            for (int i = 0; i < 4; ++i) {
                baseg[i] = bg[i] + bgd_g;
                based[i] = bd[i] + bgd_d;
                float gate = ag[i] + baseg[i];
                float dyn = ad[i] + based[i];
                float tau = sp_(at[i] + btau);
                float ki = (sigm_(gate) * tanhf(dyn) - hreg[i]) / (tau + lk);
                rk1[i] = ki;
                float yn = hreg[i] + dt4[i] * ki * (1.f / 3.f);
                ycur[i] = yn;
                sh.ypbuf[ypw + (quad * 4 + i) * 16] = f2bf_(yn);
            }
            __syncthreads();
            st64x<FAST>((ull*)p.yapack + g * 2048 + j * 256 + tid,
                        ((const ull*)sh.ypbuf)[tid]);
        }
        gsyncT<FAST>(flags, j, ++cnt);

        // ---------- stages 2..4 ----------
        #pragma unroll 1
        for (int stage = 2; stage <= 4; ++stage) {
            const unsigned short* ysrc =
                (stage == 2) ? p.yapack : (stage == 3) ? p.ybpack : p.yapack;
            unsigned short* ydst =
                (stage == 2) ? p.ybpack : (stage == 3) ? p.yapack : p.hpack;
            {
                const unsigned short* src = ysrc + g * 8192;
                uintx4 av[4];
                #pragma unroll
                for (int i = 0; i < 4; ++i)
                    ld16x<FAST>(av[i], src + (size_t)tid * 8 + i * 2048);
                vmwait4(av[0], av[1], av[2], av[3]);
                #pragma unroll
                for (int i = 0; i < 4; ++i)
                    ((uintx4*)sh.AsL)[tid + i * 256] = av[i];
            }
            __syncthreads();
            floatx4 ag = {0.f, 0.f, 0.f, 0.f};
            floatx4 ad = {0.f, 0.f, 0.f, 0.f};
            floatx4 at = {0.f, 0.f, 0.f, 0.f};
            #pragma unroll
            for (int kb = 0; kb < 16; ++kb) {
                short8 a = *(const short8*)(sh.AsL + kb * 512 + aoff);
                ag = __builtin_amdgcn_mfma_f32_16x16x32_bf16(a, wg[kb], ag, 0, 0, 0);
                ad = __builtin_amdgcn_mfma_f32_16x16x32_bf16(a, wd[kb], ad, 0, 0, 0);
                at = __builtin_amdgcn_mfma_f32_16x16x32_bf16(a, wt[kb], at, 0, 0, 0);
            }
            const int lane_p = ((c >> 3) & 3) * 16;
            #pragma unroll
            for (int i = 0; i < 4; ++i) {
                float gate = ag[i] + baseg[i];
                float dyn = ad[i] + based[i];
                float tau = sp_(at[i] + btau);
                float ki = (sigm_(gate) * tanhf(dyn) - ycur[i]) / (tau + lk);
                float yn;
                if (stage == 2) {
                    rk2[i] = ki;
                    yn = hreg[i] + dt4[i] * (ki - rk1[i] * (1.f / 3.f));
                } else if (stage == 3) {
                    rk3[i] = ki;
                    yn = hreg[i] + dt4[i] * (rk1[i] - rk2[i] + ki);
                } else {
                    yn = hreg[i] +
                         dt4[i] * (rk1[i] + 3.f * rk2[i] + 3.f * rk3[i] + ki) * 0.125f;
                    hreg[i] = yn;
                }
                ycur[i] = yn;
                sh.ypbuf[ypw + (quad * 4 + i) * 16] = f2bf_(yn);
                if (stage == 4)
                    sh.As2[(wave >> 1) * 512 + (c & 7) +
                           (lane_p + quad * 4 + i) * 8] = f2bf_(yn);
            }
            __syncthreads();
            st64x<FAST>((ull*)ydst + g * 2048 + j * 256 + tid,
                        ((const ull*)sh.ypbuf)[tid]);
            if (stage == 4) {
                #pragma unroll
                for (int h4 = 0; h4 < 4; ++h4) {
                    const int c4 = wave + h4 * 4;  // 0..15 (0..7=K, 8..15=V)
                    floatx4 acc = {0.f, 0.f, 0.f, 0.f};
                    #pragma unroll
                    for (int kk2 = 0; kk2 < 2; ++kk2) {
                        short8 a = *(const short8*)(sh.As2 + (kk2 * 64 + lane) * 8);
                        acc = __builtin_amdgcn_mfma_f32_16x16x32_bf16(
                            a, Wkv8[(c4 * 16 + (j * 2 + kk2)) * 64 + lane], acc,
                            0, 0, 0);
                    }
                    const int ac = (c4 & 7) * 16 + (lane & 15);
                    float* part = (c4 < 8) ? p.Kpart : p.Vpart;
                    #pragma unroll
                    for (int i = 0; i < 4; ++i)
                        stfx<FAST>(part +
                                       ((g * 8 + j) * 16 + quad * 4 + i) * 128 +
                                       ac,
                                   acc[i]);
                }
            }
            gsyncT<FAST>(flags, j, ++cnt);
        }
    }

    // ---------- write final h, then fc ----------
    #pragma unroll
    for (int i = 0; i < 4; ++i)
        stfx<FAST>(p.h + (g * 16 + quad * 4 + i) * H_ + c, hreg[i]);
    gsyncT<FAST>(flags, j, ++cnt);
    {
        const int o = tl & 31, ks = tl >> 5;  // ks 0..3
        float acc = 0.f;
        const float* hrow = p.h + r * H_ + ks * 128;
        const float* wcol = p.W_fc + ks * 128 * O_ + o;
        #pragma unroll 1
        for (int rd = 0; rd < 4; ++rd) {
            uintx4 hh[8];
            #pragma unroll
            for (int i = 0; i < 8; ++i)
                ld16x<FAST>(hh[i], hrow + rd * 32 + i * 4);
            vmwait8(hh[0], hh[1], hh[2], hh[3], hh[4], hh[5], hh[6], hh[7]);
            #pragma unroll
            for (int i = 0; i < 8; ++i) {
                floatx4 f = u2f_(hh[i]);
                #pragma unroll
                for (int e = 0; e < 4; ++e)
                    acc += f[e] * wcol[(rd * 32 + i * 4 + e) * O_];
            }
        }
        sh.sc4[sub][tl] = acc;
        __syncthreads();
        if (ks == 0)
            p.out[r * O_ + o] = acc + sh.sc4[sub][o + 32] + sh.sc4[sub][o + 64] +
                                sh.sc4[sub][o + 96] + p.b_fc[o];
    }
}

__global__ __launch_bounds__(256, 1) void fused_kernel(P p) {
    __shared__ Shm sh;
    const int tid = threadIdx.x;
    const int bid = blockIdx.x;
    unsigned* xtra = p.bar + 8192;  // roster[0..7], arrive[8], yes[9],
                                    // voted[10], leftover[11]

    // ---- R16 handshake: placement-agnostic same-XCD grouping.
    // Phase 0 (roster): tid0 reads physical XCC_ID, takes rank =
    //   atomicAdd(roster[xcd]) (device-scope, cross-XCD coherent), drains it
    //   to MALL (vmcnt), THEN bumps arrive[8]. arrive==128 therefore implies
    //   every roster add is final. Arrival poll BOUNDED (4096).
    // Phase 1 (vote): all 128 blocks vote "saw all arrivals"; dynamic slots
    //   adopted iff yes==128 -> mapping uniform in every outcome. The vote
    //   poll terminates whenever all blocks execute (baseline liveness).
    // Phase 2 (slots): full_x = roster[x] & ~7. Blocks with rank < full_x get
    //   slot = prefix_full[x] + rank -> every 8-aligned group inside a full
    //   region is same-XCD FOR ANY PLACEMENT (chunked, round-robin, ragged).
    //   Leftovers take slot = total_full + atomicAdd(leftover) -> mixed
    //   groups, which simply fail the probe and run the slow path.
    //   slot -> g = slot/8, j = slot%8 (bijection; work partition symmetric).
    // Phase 3 (probe+trial, bounded 384): sc0-only visibility through the
    //   exact main-loop path. Phase 4 (verdict): per-group unanimous AND via
    //   the always-correct MALL path. All cross-block traffic is intra-group,
    //   so per-group fast/slow choice is safe.
    if (tid == 0) {
        unsigned myxcc;
        asm volatile("s_getreg_b32 %0, hwreg(HW_REG_XCC_ID)" : "=s"(myxcc));
        myxcc &= 7u;
        unsigned rank = atomicAdd(&xtra[myxcc], 1u);
        asm volatile("s_waitcnt vmcnt(0)" ::: "memory");  // roster add -> MALL
        atomicAdd(&xtra[8], 1u);
        unsigned seen = 0;
        for (int it = 0; it < 4096; ++it) {
            seen = ldu32x<false>(&xtra[8]);
            if (seen >= 128u) break;
            __builtin_amdgcn_s_sleep(2);
        }
        bool localok = (seen >= 128u);
        atomicAdd(&xtra[9], localok ? 1u : 0u);
        atomicAdd(&xtra[10], 1u);
        while (ldu32x<false>(&xtra[10]) < 128u) __builtin_amdgcn_s_sleep(1);
        bool dynok = (ldu32x<false>(&xtra[9]) == 128u);
        if (dynok) {
            unsigned n[8];
            #pragma unroll
            for (int i = 0; i < 8; ++i) n[i] = ldu32x<false>(&xtra[i]);
            unsigned pre = 0, total_full = 0;
            #pragma unroll
            for (int i = 0; i < 8; ++i) {
                unsigned f = n[i] & ~7u;
                if ((unsigned)i < myxcc) pre += f;
                total_full += f;
            }
            unsigned fullme = n[myxcc] & ~7u;
            unsigned slot;
            if (rank < fullme) slot = pre + rank;               // same-XCD group
            else slot = total_full + atomicAdd(&xtra[11], 1u);  // mixed group
            sh.gj[0] = (int)(slot >> 3);
            sh.gj[1] = (int)(slot & 7u);
            sh.gj[2] = 1;
        } else {
            sh.gj[0] = bid & 15;
            sh.gj[1] = bid >> 4;
            sh.gj[2] = 0;
        }
    }
    __syncthreads();
    const int g = sh.gj[0];
    const int j = sh.gj[1];
    const bool rosterok = sh.gj[2] != 0;
    unsigned* flags = p.bar + g * 512;

    bool fast = false;
    if (rosterok) {
        // Probe: bounded sc0-only visibility check within the group. Slots
        // +32/+33 live on the 2nd 128B line of the block's 256B flag slot and
        // are only ever touched sc0-only.
        if (tid == 0) stu32x<true>(flags + j * 64 + 32, 1u);
        if (tid < 8) {
            unsigned v = 0;
            for (int it = 0; it < 384; ++it) {
                v = ldu32x<true>(flags + tid * 64 + 32);
                if (v) break;
                __builtin_amdgcn_s_sleep(2);
            }
            sh.xcs[tid] = v ? 1u : 0u;
        }
        __syncthreads();
        bool ok8 = true;
        #pragma unroll
        for (int i = 0; i < 8; ++i) ok8 = ok8 && (sh.xcs[i] != 0u);
        __syncthreads();

        // Trial: one more bounded round through the exact main-loop
        // mechanism. Probe-failed blocks never store -> participants time
        // out -> unanimous fail below.
        bool trial_ok = false;
        if (ok8) {
            if (tid == 0) stu32x<true>(flags + j * 64 + 33, 1u);
            if (tid < 8) {
                unsigned v = 0;
                for (int it = 0; it < 384; ++it) {
                    v = ldu32x<true>(flags + tid * 64 + 33);
                    if (v) break;
                    __builtin_amdgcn_s_sleep(2);
                }
                sh.xcs[tid] = v ? 1u : 0u;
            }
            __syncthreads();
            trial_ok = true;
            #pragma unroll
            for (int i = 0; i < 8; ++i)
                trial_ok = trial_ok && (sh.xcs[i] != 0u);
            __syncthreads();
        }

        // Verdict: unanimous AND over the always-correct MALL path. Every
        // block stores -> the poll always terminates.
        if (tid == 0) stu32x<false>(flags + j * 64 + 1, trial_ok ? 2u : 1u);
        if (tid < 8) {
            unsigned v;
            while ((v = ldu32x<false>(flags + tid * 64 + 1)) == 0u)
                __builtin_amdgcn_s_sleep(1);
            sh.xcs[tid] = (v == 2u) ? 1u : 0u;
        }
        __syncthreads();
        fast = true;
        #pragma unroll
        for (int i = 0; i < 8; ++i) fast = fast && (sh.xcs[i] != 0u);
    }

    if (fast)
        run_body<true>(p, sh, g, j);   // XCD-L2 exchange (~200 cy round trips)
    else
        run_body<false>(p, sh, g, j);  // MALL exchange (R11 behavior)
}

extern "C" void kernel_launch(void* const* d_in, const int* in_sizes, int n_in,
                              void* d_out, int out_size, void* d_ws,
                              size_t ws_size, hipStream_t stream) {
    (void)in_sizes; (void)n_in; (void)out_size; (void)ws_size;
    P p;
    p.x = (const float*)d_in[0];
    p.dts = (const float*)d_in[1];
    p.Wq = (const float*)d_in[2];
    p.bq = (const float*)d_in[3];
    const float* Wk = (const float*)d_in[4];
    p.bk = (const float*)d_in[5];
    const float* Wv = (const float*)d_in[6];
    p.bv = (const float*)d_in[7];
    const float* W_gd = (const float*)d_in[8];
    p.b_gd = (const float*)d_in[9];
    const float* W_tau = (const float*)d_in[10];
    p.b_tau = (const float*)d_in[11];
    p.gleak = (const float*)d_in[12];
    p.cm = (const float*)d_in[13];
    p.W_fc = (const float*)d_in[14];
    p.b_fc = (const float*)d_in[15];
    p.out = (float*)d_out;

    float* ws = (float*)d_ws;
    p.h = ws;                            // B*H fp32
    p.ctx = p.h + B_ * H_;               // B*A fp32
    p.Kpart = p.ctx + B_ * A_;           // 128*16*128 fp32
    p.Vpart = p.Kpart + 262144;
    unsigned short* Wpack = (unsigned short*)(p.Vpart + 262144);
    p.Wy = Wpack;                        // 786432 ushorts
    p.Wx = Wpack + 786432;               // 65536
    p.Wc = Wpack + 851968;               // 131072
    p.Wkv = Wpack + 983040;              // 131072
    p.hpack = Wpack + 1114112;           // B*H ushorts, strip-tile layout
    p.yapack = p.hpack + B_ * H_;
    p.ybpack = p.yapack + B_ * H_;
    p.Kh = p.ybpack + B_ * H_;           // B*T*A bf16 (block-private rows)
    p.bar = (unsigned*)(p.Kh + (size_t)B_ * T_ * A_);  // 8192+64 uints

    init_kernel<<<512, 256, 0, stream>>>(p.hpack, p.bar);
    pack_w_kernel<<<4352, 256, 0, stream>>>(W_gd, W_tau, Wk, Wv, Wpack);

    // 128 blocks x 256 threads, launch_bounds(256,1).
    // R13 post-mortem: strided-by-16 groups spanned XCDs (probe timeout,
    // +900us). R15 post-mortem: XCD roster is NOT 16-per-XCD even (evenness
    // gate fell through at +120us; placement is chunked/ragged).
    // R16: prefix-sum slotting over floor(n_x/8)*8 makes every full group
    // same-XCD for ANY placement; leftovers form mixed groups that fail the
    // bounded probe and run the R11 MALL path. Same-XCD groups verify the
    // sc0-only (XCD-L2) exchange via bounded probe+trial and adopt it on a
    // per-group unanimous MALL verdict.
    fused_kernel<<<dim3(128), dim3(256), 0, stream>>>(p);
}